// Round 9
// baseline (333.827 us; speedup 1.0000x reference)
//
#include <hip/hip_runtime.h>
#include <math.h>

#define PI_D 3.14159265358979323846
#define TWO_PI_F 6.2831853071795864f

// ---------------- persistent device buffers ---------------------------------
__device__ __align__(16) float2 g_Mf [128*128];
__device__ __align__(16) float2 g_MfT[128*128];
__device__ __align__(16) float2 g_Mb [128*128];
__device__ __align__(16) float2 g_MbT[128*128];
__device__ __align__(16) float2 g_F  [128*128];   // symmetric
__device__ __align__(16) float2 g_IF [128*128];   // symmetric
__device__ __align__(16) float  g_x1 [4*48*16384];
__device__ __align__(16) float2 g_bufA[64*16384];
__device__ __align__(16) float2 g_bufB[64*16384];
__device__ __align__(16) float  g_mag[64*16384];
__device__ __align__(16) float  g_pha[64*16384];
__device__ __align__(16) float  g_m65[64*8320];
__device__ __align__(16) float  g_p65[64*8320];
__device__ __align__(16) float  g_t1 [64*16384];
__device__ __align__(16) float  g_t2 [64*16384];
__device__ __align__(16) float  g_t3 [64*8320];
__device__ __align__(16) float  g_t4 [64*8320];
__device__ __align__(16) float  g_cat[4*48*16384];

// ---------------- builder body -----------------------------------------------
__device__ inline void build_A_body(int tid) {
    if (tid >= 128*128) return;
    int o = tid >> 7, m = tid & 127;
    const double chc = -PI_D/128.0 * tan(PI_D/8.0) * 0.25;
    const double c   =  PI_D/(512.0*sin(PI_D/4.0));
    const double inv2pi = 1.0/(2.0*PI_D);
    float sr, si;
    {   // q = 2m term (sinc = 1)
        int n1 = 2*m - 127, tt = 2*(o - m);
        double ang = chc*(double)(n1*n1) + c*(double)(tt*tt);
        double r = ang*inv2pi; r -= floor(r);
        float af = (float)(r*2.0*PI_D);
        float sn, cs; __sincosf(af, &sn, &cs);
        sr = cs; si = sn;
    }
    for (int j = 0; j < 127; ++j) {
        int q  = 2*j + 1;
        int n1 = q - 127, tt = 2*o - q, d = q - 2*m;
        double ang = chc*(double)(n1*n1) + c*(double)(tt*tt);
        double r = ang*inv2pi; r -= floor(r);
        float af = (float)(r*2.0*PI_D);
        float s = (((d-1)>>1) & 1) ? -2.0f : 2.0f;
        s /= (3.14159265358979f*(float)d);
        float sn, cs; __sincosf(af, &sn, &cs);
        sr += s*cs; si += s*sn;
    }
    int n2 = 2*o - 127;
    double ph = chc*(double)(n2*n2) - PI_D/8.0;
    double r = ph*inv2pi; r -= floor(r);
    float pf = (float)(r*2.0*PI_D);
    float scale = (float)sqrt(c/PI_D);
    float sn, cs; __sincosf(pf, &sn, &cs);
    float cr = cs*scale, ci = sn*scale;
    float2 v = make_float2(sr*cr - si*ci, sr*ci + si*cr);
    g_Mf[tid] = v;
    g_MfT[(m<<7) + o] = v;
    int p = (o*m) & 127;
    float ang2 = TWO_PI_F*(float)p/128.0f;
    float sn2, cs2; __sincosf(ang2, &sn2, &cs2);
    g_F[tid]  = make_float2(cs2, -sn2);
    g_IF[tid] = make_float2(cs2*0.0078125f, sn2*0.0078125f);
}

// ---------------- stream loaders (stage-5 rmul staging) ----------------------
template<int LM>
__device__ inline void load_T4(float2* tr, const float* mp, const float* pp,
                               int hh, int w4) {
    if (LM == 2) {
#pragma unroll
        for (int i = 0; i < 4; ++i) {
            int idx = (hh<<7) + w4 + i;
            float m = mp[idx], ph = pp[idx];
            float sn, cs; __sincosf(ph, &sn, &cs);
            tr[i] = make_float2(m*cs, m*sn);
        }
    } else {
#pragma unroll
        for (int i = 0; i < 4; ++i) {
            int w = w4 + i;
            int h2 = hh, w2 = w; float sg = 1.f;
            if (w >= 65) { h2 = (128 - hh) & 127; w2 = 128 - w; sg = -1.f; }
            int idx = h2*65 + w2;
            float m = mp[idx], ph = pp[idx];
            float sn, cs; __sincosf(ph, &sn, &cs);
            tr[i] = make_float2(m*cs, sg*m*sn);
        }
    }
}

__device__ inline void cfma(float2& a, float sx, float sy, float mx, float my) {
    a.x = fmaf(sx, mx, a.x); a.x = fmaf(-sy, my, a.x);
    a.y = fmaf(sx, my, a.y); a.y = fmaf(sy, mx, a.y);
}

// ---------------- rmul RS (stage 2): out[p,h,j] = sum_w T[p,h,w] * A[j,w] ----
// w-split geometry: 64 j-columns/block (1 complex/lane), 16 h-rows/block,
// grid (136,16) with by=(y&7) strip, ws=(y>>3)*64 -> 2048 compute blocks =
// 8 blocks/CU = 32 waves/CU (max TLP). Stream rows via wave-uniform (scalar)
// loads; m-side direct global; zero LDS, zero barriers in compute path.
__global__ __launch_bounds__(256, 8)
void k_rmul_rs(const float2* __restrict__ MTa, const float* __restrict__ TrlA,
               float2* __restrict__ outA, int cstartA,
               const float2* __restrict__ MTb, const float* __restrict__ TrlB,
               float2* __restrict__ outB, int cstartB) {
    __shared__ float2 W[128];
    int bx = blockIdx.x, y = blockIdx.y, t = threadIdx.x;
    int by = y & 7, z = y >> 3;
    if (bx >= 128) {
        if (z != 0) return;
        int b = (bx - 128)*8 + by;
        if (b < 64) {
            if (t < 128) {
                float ang = TWO_PI_F*(float)t/128.0f;
                float sn, cs; __sincosf(ang, &sn, &cs);
                float invs = 0.08838834764831845f;
                W[t] = make_float2(cs*invs, sn*invs);
            }
            __syncthreads();
            int tid = b*256 + t;
            int o = tid >> 7, m = tid & 127;
            float sr = 0.f, si = 0.f;
            for (int r = 0; r < 128; ++r) {
                float2 a = g_Mf[(o<<7) + r];
                int k = ((r+64)*(m+64)) & 127;
                float2 w = W[k];
                sr += a.x*w.x - a.y*w.y;
                si += a.x*w.y + a.y*w.x;
            }
            float2 v = make_float2(sr, si);
            g_Mb[tid] = v;
            g_MbT[(m<<7) + o] = v;
        }
        return;
    }
    int p = bx & 63, r0 = by << 4, ws = z << 6;
    const float2* MT; const float* Trl; float2* out; int cstart;
    if (bx < 64) { MT = MTa; Trl = TrlA; out = outA; cstart = cstartA; }
    else         { MT = MTb; Trl = TrlB; out = outB; cstart = cstartB; }
    int n = p >> 4, c = p & 15;
    const float* Trp = Trl + ((long)(n*48 + cstart + c) << 14);
    int lane = t & 63, rp = t >> 6;
    const float* Tr_row[4];
#pragma unroll
    for (int i = 0; i < 4; ++i) {
        int ro = __builtin_amdgcn_readfirstlane((r0 + (rp<<2) + i) << 7);
        Tr_row[i] = Trp + ro;
    }
    const float2* Mc = MT + ws + lane;
    float2 acc[4] = {};
#pragma unroll 8
    for (int k2 = 0; k2 < 64; ++k2) {
        int k = k2 << 1;
        float2 m0 = Mc[(k  ) << 7];
        float2 m1 = Mc[(k+1) << 7];
        float2 sr[4];
#pragma unroll
        for (int i = 0; i < 4; ++i)
            sr[i] = *(const float2*)(Tr_row[i] + k);
#pragma unroll
        for (int i = 0; i < 4; ++i) {
            acc[i].x = fmaf(sr[i].x, m0.x, acc[i].x);
            acc[i].y = fmaf(sr[i].x, m0.y, acc[i].y);
            acc[i].x = fmaf(sr[i].y, m1.x, acc[i].x);
            acc[i].y = fmaf(sr[i].y, m1.y, acc[i].y);
        }
    }
    long base = ((long)p << 14);
#pragma unroll
    for (int i = 0; i < 4; ++i)
        *(float2*)(out + base + ((long)(r0 + (rp<<2) + i) << 7) + ws + lane) = acc[i];
}

// ---------------- lmul (stages 3/6): out[p,j,w] = sum_h A[j,h] * T[p,h,w] ----
// w-split geometry: 64 w/block (1 complex/lane), 16 j-rows/block, grid
// (128,16) -> 2048 blocks = 8 blocks/CU = 32 waves/CU. A-side via scalar
// loads; T-side direct global. EPI 1: mag/pha  2: abs->cat  3: real->cat
// 4: packed65
template<int EPI>
__device__ inline void lmul_body(const float2* __restrict__ A, const float2* __restrict__ in,
                                 float* __restrict__ o1, float* __restrict__ o2, int coff,
                                 int p, int j0, int ws, int t) {
    const float2* T = in + ((long)p << 14);
    int lane = t & 63, rp = t >> 6;
    const float2* Arow[4];
#pragma unroll
    for (int i = 0; i < 4; ++i) {
        int ro = __builtin_amdgcn_readfirstlane((j0 + (rp<<2) + i) << 7);
        Arow[i] = A + ro;
    }
    const float2* Tc = T + ws + lane;
    float2 acc[4] = {};
#pragma unroll 8
    for (int k2 = 0; k2 < 64; ++k2) {
        int k = k2 << 1;
        float2 m0 = Tc[(k  ) << 7];
        float2 m1 = Tc[(k+1) << 7];
        float4 s2[4];
#pragma unroll
        for (int i = 0; i < 4; ++i)
            s2[i] = *(const float4*)(Arow[i] + k);
#pragma unroll
        for (int i = 0; i < 4; ++i) {
            if (EPI == 3) {
                acc[i].x = fmaf(s2[i].x, m0.x, acc[i].x);
                acc[i].x = fmaf(-s2[i].y, m0.y, acc[i].x);
                acc[i].x = fmaf(s2[i].z, m1.x, acc[i].x);
                acc[i].x = fmaf(-s2[i].w, m1.y, acc[i].x);
            } else {
                cfma(acc[i], s2[i].x, s2[i].y, m0.x, m0.y);
                cfma(acc[i], s2[i].z, s2[i].w, m1.x, m1.y);
            }
        }
    }
#pragma unroll
    for (int i = 0; i < 4; ++i) {
        int jj = j0 + (rp<<2) + i;
        int w = ws + lane;
        float2 v = acc[i];
        if (EPI == 1) {
            long idx = ((long)p << 14) + ((long)jj << 7) + w;
            o1[idx] = sqrtf(v.x*v.x + v.y*v.y);
            o2[idx] = atan2f(v.y, v.x);
        } else if (EPI == 2) {
            int n = p >> 4, c = p & 15;
            long idx = ((long)(n*48 + coff + c) << 14) + ((long)jj << 7) + w;
            o1[idx] = sqrtf(v.x*v.x + v.y*v.y);
        } else if (EPI == 3) {
            int n = p >> 4, c = p & 15;
            long idx = ((long)(n*48 + coff + c) << 14) + ((long)jj << 7) + w;
            o1[idx] = v.x;
        } else if (EPI == 4) {
            if (w < 65) {
                long idx = (long)p*8320 + jj*65 + w;
                o1[idx] = sqrtf(v.x*v.x + v.y*v.y);
                o2[idx] = atan2f(v.y, v.x);
            }
        }
    }
}

template<int EPIA, int EPIB>
__global__ __launch_bounds__(256, 8)
void k_lmul_dual(const float2* __restrict__ Aa, const float2* __restrict__ inA,
                 float* __restrict__ o1A, float* __restrict__ o2A, int coffA,
                 const float2* __restrict__ Ab, const float2* __restrict__ inB,
                 float* __restrict__ o1B, float* __restrict__ o2B, int coffB) {
    int bx = blockIdx.x, y = blockIdx.y, t = threadIdx.x;
    int j0 = (y & 7) << 4, ws = (y >> 3) << 6;
    int p = bx & 63;
    if (bx < 64) lmul_body<EPIA>(Aa, inA, o1A, o2A, coffA, p, j0, ws, t);
    else         lmul_body<EPIB>(Ab, inB, o1B, o2B, coffB, p, j0, ws, t);
}

// ---------------- rmul CM (stage 5) — round-5 geometry, LDS s-side ----------
// 4 blocks/CU, full 128-wide, Ssh staged via sincos (one barrier), m-side
// direct-global float4 reads.
template<int LM>
__device__ inline void rmul_cm_body(const float2* __restrict__ MT, const float* __restrict__ mp_,
                                    const float* __restrict__ pp_, float2* __restrict__ out,
                                    int p, int r0, int t, float2* Ssh) {
    const float* mp; const float* pp;
    if (LM == 2) { mp = mp_ + ((long)p << 14); pp = pp_ + ((long)p << 14); }
    else         { mp = mp_ + (long)p*8320;   pp = pp_ + (long)p*8320; }
    int cq = t & 63, rp = t >> 6;
    for (int u = t; u < 512; u += 256) {
        int row = u >> 5, w4 = (u & 31) << 2;
        float2 tr4[4];
        load_T4<LM>(tr4, mp, pp, r0 + row, w4);
        float4* d = (float4*)&Ssh[(row << 7) + w4];
        d[0] = make_float4(tr4[0].x, tr4[0].y, tr4[1].x, tr4[1].y);
        d[1] = make_float4(tr4[2].x, tr4[2].y, tr4[3].x, tr4[3].y);
    }
    __syncthreads();
    float2 acc[4][2] = {};
#pragma unroll 8
    for (int k2 = 0; k2 < 64; ++k2) {
        int k = k2 << 1;
        float4 m0 = *(const float4*)&MT[(k << 7) + (cq<<1)];
        float4 m1 = *(const float4*)&MT[((k+1) << 7) + (cq<<1)];
        float4 s2[4];
#pragma unroll
        for (int i = 0; i < 4; ++i)
            s2[i] = *(const float4*)&Ssh[(((rp<<2)+i) << 7) + k];
#pragma unroll
        for (int i = 0; i < 4; ++i) {
            cfma(acc[i][0], s2[i].x, s2[i].y, m0.x, m0.y);
            cfma(acc[i][1], s2[i].x, s2[i].y, m0.z, m0.w);
            cfma(acc[i][0], s2[i].z, s2[i].w, m1.x, m1.y);
            cfma(acc[i][1], s2[i].z, s2[i].w, m1.z, m1.w);
        }
    }
    long base = ((long)p << 14);
#pragma unroll
    for (int i = 0; i < 4; ++i) {
        float4* dst = (float4*)(out + base + ((long)(r0 + (rp<<2) + i) << 7) + (cq<<1));
        *dst = make_float4(acc[i][0].x, acc[i][0].y, acc[i][1].x, acc[i][1].y);
    }
}

template<int LMA, int LMB>
__global__ __launch_bounds__(256, 4)
void k_rmul_cm(const float2* __restrict__ MTa, const float* __restrict__ mpA,
               const float* __restrict__ ppA, float2* __restrict__ outA,
               const float2* __restrict__ MTb, const float* __restrict__ mpB,
               const float* __restrict__ ppB, float2* __restrict__ outB) {
    __shared__ __align__(16) float2 Ssh[16*128];
    int bx = blockIdx.x, r0 = blockIdx.y << 4, t = threadIdx.x;
    int p = bx & 63;
    if (bx < 64) rmul_cm_body<LMA>(MTa, mpA, ppA, outA, p, r0, t, Ssh);
    else         rmul_cm_body<LMB>(MTb, mpB, ppB, outB, p, r0, t, Ssh);
}

// ---------------- wave-level 1x1 conv body -----------------------------------
template<int CIN, int COUT, int KSPLIT, int OSPLIT>
__device__ inline void wconv_body(const float* __restrict__ in, const float* __restrict__ wgt,
                                  const float* __restrict__ bias, float* __restrict__ out,
                                  int S, int Ctin, int cstart, int Ctout, int costart,
                                  int n, int sblk, float* red) {
    constexpr int OW = COUT / OSPLIT;
    constexpr int KC = CIN / KSPLIT;
    int t = threadIdx.x, lane = t & 63;
    int wv = __builtin_amdgcn_readfirstlane(t >> 6);
    int oq = wv / KSPLIT, kq = wv % KSPLIT;
    int s0 = sblk << 7;
    const float* inb = in + ((long)(n*Ctin + cstart + kq*KC))*S + s0 + (lane<<1);
    const float* wb  = wgt + (oq*OW)*CIN + kq*KC;
    float2 acc[OW];
#pragma unroll
    for (int j = 0; j < OW; ++j) acc[j] = make_float2(0.f, 0.f);
#pragma unroll 4
    for (int c = 0; c < KC; ++c) {
        float2 xv = *(const float2*)(inb + (long)c*S);
#pragma unroll
        for (int j = 0; j < OW; ++j) {
            float w = wb[j*CIN + c];
            acc[j].x = fmaf(w, xv.x, acc[j].x);
            acc[j].y = fmaf(w, xv.y, acc[j].y);
        }
    }
    if (KSPLIT == 1) {
#pragma unroll
        for (int j = 0; j < OW; ++j) {
            int o = oq*OW + j;
            float b = bias ? bias[o] : 0.f;
            *(float2*)(out + ((long)(n*Ctout + costart + o))*S + s0 + (lane<<1))
                = make_float2(acc[j].x + b, acc[j].y + b);
        }
    } else {
#pragma unroll
        for (int j = 0; j < OW; ++j) {
            int o = oq*OW + j;
            *(float2*)&red[((kq*COUT + o) << 7) + (lane<<1)] = acc[j];
        }
        __syncthreads();
        for (int idx = t; idx < COUT*64; idx += 256) {
            int o = idx >> 6, l2 = (idx & 63) << 1;
            float b = bias ? bias[o] : 0.f;
            float2 v = make_float2(b, b);
#pragma unroll
            for (int k2 = 0; k2 < KSPLIT; ++k2) {
                float2 r = *(const float2*)&red[((k2*COUT + o) << 7) + l2];
                v.x += r.x; v.y += r.y;
            }
            *(float2*)(out + ((long)(n*Ctout + costart + o))*S + s0 + l2) = v;
        }
    }
}

// ---------------- stage 1: conv1 + matrix builder ----------------------------
__global__ __launch_bounds__(256, 1)
void k_conv1_build(const float* __restrict__ x, const float* __restrict__ w,
                   float* __restrict__ x1) {
    __shared__ float red[2*48*128];
    if (blockIdx.z == 0) {
        wconv_body<192,48,2,2>(x, w, nullptr, x1, 16384, 192, 0, 48, 0,
                               blockIdx.y, blockIdx.x, red);
    } else {
        int b = blockIdx.y*gridDim.x + blockIdx.x;
        if (b < 64) build_A_body(b*256 + threadIdx.x);
    }
}

// ---------------- stage 7: conv2 ---------------------------------------------
__global__ __launch_bounds__(256, 1)
void k_conv2(const float* __restrict__ in, const float* __restrict__ wgt,
             float* __restrict__ out) {
    __shared__ float red[1];
    wconv_body<48,192,1,4>(in, wgt, nullptr, out, 16384, 48, 0, 192, 0,
                           blockIdx.y, blockIdx.x, red);
}

// ---------------- pointwise stage: maskconv + 4 channel-mixes ----------------
__device__ inline void mix16b(const float* __restrict__ in, const float* __restrict__ w,
                              const float* __restrict__ b, float* __restrict__ out,
                              int Ctin, int S, int n, int s0base, int Slim) {
    int t = threadIdx.x, lane = t & 63;
    int wv = __builtin_amdgcn_readfirstlane(t >> 6);
    int oq = wv & 3, pg = wv >> 2;
    int s0 = s0base + (pg << 7);
    if (s0 >= Slim) return;                    // no __syncthreads in this path
    const float* inb = in + ((long)(n*Ctin))*S + s0 + (lane<<1);
    float2 acc[4];
#pragma unroll
    for (int j = 0; j < 4; ++j) {
        float bb = b ? b[oq*4 + j] : 0.f;
        acc[j] = make_float2(bb, bb);
    }
#pragma unroll
    for (int half = 0; half < 2; ++half) {
        float2 xv[8];
#pragma unroll
        for (int c = 0; c < 8; ++c)
            xv[c] = *(const float2*)(inb + (long)(half*8 + c)*S);
#pragma unroll
        for (int c = 0; c < 8; ++c) {
#pragma unroll
            for (int j = 0; j < 4; ++j) {
                float ww = w[(oq*4 + j)*16 + half*8 + c];
                acc[j].x = fmaf(ww, xv[c].x, acc[j].x);
                acc[j].y = fmaf(ww, xv[c].y, acc[j].y);
            }
        }
    }
#pragma unroll
    for (int j = 0; j < 4; ++j) {
        int o = oq*4 + j;
        *(float2*)(out + ((long)(n*Ctin + o))*S + s0 + (lane<<1)) = acc[j];
    }
}

__device__ inline void maskconv_body(const float* __restrict__ mag, const float* __restrict__ ws3,
                                     const float* __restrict__ bs, const float* __restrict__ wf,
                                     const float* __restrict__ bf, const float* __restrict__ wm,
                                     const float* __restrict__ bm, float* __restrict__ out,
                                     int n, int tile, float* patch) {
    int h0 = (tile >> 3) << 4, w0 = (tile & 7) << 4;
    int t = threadIdx.x;
    const float* magn = mag + ((long)n << 18);
    for (int idx = t; idx < 16*324; idx += 1024) {
        int c = idx / 324, r = idx - c*324;
        int ph = r / 18, pw = r - ph*18;
        int gh = h0 - 1 + ph, gw = w0 - 1 + pw;
        float v = 0.f;
        if (gh >= 19 && gh < 109 && gw >= 19 && gw < 109)
            v = magn[(c<<14) + (gh<<7) + gw];
        patch[c*324 + r] = v;
    }
    __syncthreads();
    int oq = t >> 8, pix = t & 255;
    int ty = pix >> 4, tx = pix & 15;
    int h = h0 + ty, w = w0 + tx;
    bool in1 = (h >= 19 && h < 109 && w >= 19 && w < 109);
    unsigned long long bal = __ballot(in1);
    float res[4];
    if (bal != 0ull) {
        float acc[4];
#pragma unroll
        for (int j = 0; j < 4; ++j) acc[j] = bs[oq*4 + j];
        for (int c = 0; c < 16; ++c) {
            const float* pc = patch + c*324 + ty*18 + tx;
            const float* wc = ws3 + c*9;
#pragma unroll
            for (int dh = 0; dh < 3; ++dh) {
#pragma unroll
                for (int dw = 0; dw < 3; ++dw) {
                    float tap = pc[dh*18 + dw];
#pragma unroll
                    for (int j = 0; j < 4; ++j)
                        acc[j] = fmaf(wc[(oq*4 + j)*144 + dh*3 + dw], tap, acc[j]);
                }
            }
        }
#pragma unroll
        for (int j = 0; j < 4; ++j) res[j] = acc[j];
    }
    if (bal != ~0ull) {
        float acc2[4];
#pragma unroll
        for (int j = 0; j < 4; ++j) acc2[j] = bf[oq*4 + j];
#pragma unroll
        for (int half = 0; half < 2; ++half) {
            float xv[8];
#pragma unroll
            for (int c = 0; c < 8; ++c)
                xv[c] = magn[((half*8 + c)<<14) + (h<<7) + w];
#pragma unroll
            for (int c = 0; c < 8; ++c)
#pragma unroll
                for (int j = 0; j < 4; ++j)
                    acc2[j] = fmaf(wf[(oq*4 + j)*16 + half*8 + c], xv[c], acc2[j]);
        }
        if (!in1) {
#pragma unroll
            for (int j = 0; j < 4; ++j) res[j] = acc2[j];
        }
    }
    __syncthreads();               // all reads of patch complete
    float* resl = patch;           // reuse as [16][256]
#pragma unroll
    for (int j = 0; j < 4; ++j) resl[(oq*4 + j)*256 + pix] = res[j];
    __syncthreads();
    float rr[16];
#pragma unroll
    for (int o = 0; o < 16; ++o) rr[o] = resl[o*256 + pix];
#pragma unroll
    for (int j = 0; j < 4; ++j) {
        int o2 = oq*4 + j;
        float a = bm[o2];
#pragma unroll
        for (int o = 0; o < 16; ++o)
            a = fmaf(wm[o2*16 + o], rr[o], a);
        out[((long)((n<<4) + o2) << 14) + (h << 7) + w] = a;
    }
}

__global__ __launch_bounds__(1024, 8)
void k_point(const float* __restrict__ mag, const float* __restrict__ ws3,
             const float* __restrict__ bs, const float* __restrict__ wf,
             const float* __restrict__ bf, const float* __restrict__ wm,
             const float* __restrict__ bm, float* __restrict__ t2,
             const float* __restrict__ pha, const float* __restrict__ pw,
             const float* __restrict__ pb, float* __restrict__ t1,
             const float* __restrict__ x1, const float* __restrict__ c0w,
             const float* __restrict__ c0b, float* __restrict__ cat,
             const float* __restrict__ m65, const float* __restrict__ p65,
             const float* __restrict__ c1w, const float* __restrict__ c1b,
             float* __restrict__ t3, float* __restrict__ t4) {
    __shared__ float patch[16*324];
    int b = blockIdx.x;
    if (b < 256) {
        maskconv_body(mag, ws3, bs, wf, bf, wm, bm, t2, b >> 6, b & 63, patch);
    } else if (b < 384) {
        int i = b - 256;               // pha channel-mix (S=16384): 32 blocks/n
        mix16b(pha, pw, pb, t1, 16, 16384, i >> 5, (i & 31) << 9, 16384);
    } else if (b < 512) {
        int i = b - 384;               // conv_0: x1 ch0..15 -> cat ch0..15 (Ct=48)
        mix16b(x1, c0w, c0b, cat, 48, 16384, i >> 5, (i & 31) << 9, 16384);
    } else if (b < 580) {
        int i = b - 512;               // m65 mix (S=8320): 17 blocks/n
        mix16b(m65, c1w, c1b, t3, 16, 8320, i / 17, (i % 17) << 9, 8320);
    } else {
        int i = b - 580;               // p65 mix
        mix16b(p65, c1w, c1b, t4, 16, 8320, i / 17, (i % 17) << 9, 8320);
    }
}

// ---------------- launch ----------------------------------------------------
extern "C" void kernel_launch(void* const* d_in, const int* in_sizes, int n_in,
                              void* d_out, int out_size, void* d_ws, size_t ws_size,
                              hipStream_t stream) {
    (void)in_sizes; (void)n_in; (void)out_size; (void)d_ws; (void)ws_size;
    const float* x        = (const float*)d_in[0];
    const float* conv1_w  = (const float*)d_in[1];
    const float* mag_s_w  = (const float*)d_in[2];
    const float* mag_s_b  = (const float*)d_in[3];
    const float* mag_f_w  = (const float*)d_in[4];
    const float* mag_f_b  = (const float*)d_in[5];
    const float* mag_w_   = (const float*)d_in[6];
    const float* mag_b_   = (const float*)d_in[7];
    const float* pha_w_   = (const float*)d_in[8];
    const float* pha_b_   = (const float*)d_in[9];
    const float* conv_0_w = (const float*)d_in[10];
    const float* conv_0_b = (const float*)d_in[11];
    const float* conv_1_w = (const float*)d_in[12];
    const float* conv_1_b = (const float*)d_in[13];
    const float* conv2_w  = (const float*)d_in[14];
    float* outp = (float*)d_out;

    float2 *Mf, *MfT, *Mb, *MbT, *Fm, *IFm, *bufA, *bufB;
    float *x1, *mag, *pha, *m65, *p65, *t1, *t2, *t3, *t4, *cat;
    hipGetSymbolAddress((void**)&Mf,   HIP_SYMBOL(g_Mf));
    hipGetSymbolAddress((void**)&MfT,  HIP_SYMBOL(g_MfT));
    hipGetSymbolAddress((void**)&Mb,   HIP_SYMBOL(g_Mb));
    hipGetSymbolAddress((void**)&MbT,  HIP_SYMBOL(g_MbT));
    hipGetSymbolAddress((void**)&Fm,   HIP_SYMBOL(g_F));
    hipGetSymbolAddress((void**)&IFm,  HIP_SYMBOL(g_IF));
    hipGetSymbolAddress((void**)&bufA, HIP_SYMBOL(g_bufA));
    hipGetSymbolAddress((void**)&bufB, HIP_SYMBOL(g_bufB));
    hipGetSymbolAddress((void**)&x1,   HIP_SYMBOL(g_x1));
    hipGetSymbolAddress((void**)&mag,  HIP_SYMBOL(g_mag));
    hipGetSymbolAddress((void**)&pha,  HIP_SYMBOL(g_pha));
    hipGetSymbolAddress((void**)&m65,  HIP_SYMBOL(g_m65));
    hipGetSymbolAddress((void**)&p65,  HIP_SYMBOL(g_p65));
    hipGetSymbolAddress((void**)&t1,   HIP_SYMBOL(g_t1));
    hipGetSymbolAddress((void**)&t2,   HIP_SYMBOL(g_t2));
    hipGetSymbolAddress((void**)&t3,   HIP_SYMBOL(g_t3));
    hipGetSymbolAddress((void**)&t4,   HIP_SYMBOL(g_t4));
    hipGetSymbolAddress((void**)&cat,  HIP_SYMBOL(g_cat));

    dim3 bt(256, 1, 1);

    // stage 1: conv1 (x -> x1) + build Mf/MfT/F/IF
    k_conv1_build<<<dim3(128,4,2), bt, 0, stream>>>(x, conv1_w, x1);

    // stage 2: dual rmul RS (FRFT fwd -> bufA; FFT fwd -> bufB) + build Mb
    k_rmul_rs<<<dim3(136,16), bt, 0, stream>>>(
        MfT, x1, bufA, 16,
        Fm,  x1, bufB, 32);

    // stage 3: dual lmul (mag/pha full <- bufA; packed65 <- bufB)
    k_lmul_dual<1,4><<<dim3(128,16), bt, 0, stream>>>(
        Mf, bufA, mag, pha, 0,
        Fm, bufB, m65, p65, 0);

    // stage 4: maskconv(+mag mix) | pha mix | conv_0 | m65 mix | p65 mix
    k_point<<<648, dim3(1024,1,1), 0, stream>>>(mag, mag_s_w, mag_s_b, mag_f_w, mag_f_b,
                                                mag_w_, mag_b_, t2,
                                                pha, pha_w_, pha_b_, t1,
                                                x1, conv_0_w, conv_0_b, cat,
                                                m65, p65, conv_1_w, conv_1_b, t3, t4);

    // stage 5: dual rmul CM (FRFT bwd combine(t2,t1) -> bufA; irfft combine65 -> bufB)
    k_rmul_cm<2,3><<<dim3(128,8), bt, 0, stream>>>(
        MbT, t2, t1, bufA,
        IFm, t3, t4, bufB);

    // stage 6: dual lmul (abs -> cat ch16..31; real -> cat ch32..47)
    k_lmul_dual<2,3><<<dim3(128,16), bt, 0, stream>>>(
        Mb,  bufA, cat, nullptr, 16,
        IFm, bufB, cat, nullptr, 32);

    // stage 7: conv2 (cat -> out)
    k_conv2<<<dim3(128,4), bt, 0, stream>>>(cat, conv2_w, outp);
}

// Round 10
// 327.433 us; speedup vs baseline: 1.0195x; 1.0195x over previous
//
#include <hip/hip_runtime.h>
#include <math.h>

#define PI_D 3.14159265358979323846
#define TWO_PI_F 6.2831853071795864f

// ---------------- persistent device buffers ---------------------------------
__device__ __align__(16) float2 g_Mf [128*128];
__device__ __align__(16) float2 g_MfT[128*128];
__device__ __align__(16) float2 g_Mb [128*128];
__device__ __align__(16) float2 g_MbT[128*128];
__device__ __align__(16) float2 g_F  [128*128];   // symmetric
__device__ __align__(16) float2 g_IF [128*128];   // symmetric
__device__ __align__(16) float  g_x1 [4*48*16384];
__device__ __align__(16) float2 g_bufA[64*16384];
__device__ __align__(16) float2 g_bufB[64*16384];
__device__ __align__(16) float  g_mag[64*16384];
__device__ __align__(16) float  g_pha[64*16384];
__device__ __align__(16) float  g_m65[64*8320];
__device__ __align__(16) float  g_p65[64*8320];
__device__ __align__(16) float  g_t1 [64*16384];
__device__ __align__(16) float  g_t2 [64*16384];
__device__ __align__(16) float  g_t3 [64*8320];
__device__ __align__(16) float  g_t4 [64*8320];
__device__ __align__(16) float  g_cat[4*48*16384];

// ---------------- builder body -----------------------------------------------
__device__ inline void build_A_body(int tid) {
    if (tid >= 128*128) return;
    int o = tid >> 7, m = tid & 127;
    const double chc = -PI_D/128.0 * tan(PI_D/8.0) * 0.25;
    const double c   =  PI_D/(512.0*sin(PI_D/4.0));
    const double inv2pi = 1.0/(2.0*PI_D);
    float sr, si;
    {   // q = 2m term (sinc = 1)
        int n1 = 2*m - 127, tt = 2*(o - m);
        double ang = chc*(double)(n1*n1) + c*(double)(tt*tt);
        double r = ang*inv2pi; r -= floor(r);
        float af = (float)(r*2.0*PI_D);
        float sn, cs; __sincosf(af, &sn, &cs);
        sr = cs; si = sn;
    }
    for (int j = 0; j < 127; ++j) {
        int q  = 2*j + 1;
        int n1 = q - 127, tt = 2*o - q, d = q - 2*m;
        double ang = chc*(double)(n1*n1) + c*(double)(tt*tt);
        double r = ang*inv2pi; r -= floor(r);
        float af = (float)(r*2.0*PI_D);
        float s = (((d-1)>>1) & 1) ? -2.0f : 2.0f;
        s /= (3.14159265358979f*(float)d);
        float sn, cs; __sincosf(af, &sn, &cs);
        sr += s*cs; si += s*sn;
    }
    int n2 = 2*o - 127;
    double ph = chc*(double)(n2*n2) - PI_D/8.0;
    double r = ph*inv2pi; r -= floor(r);
    float pf = (float)(r*2.0*PI_D);
    float scale = (float)sqrt(c/PI_D);
    float sn, cs; __sincosf(pf, &sn, &cs);
    float cr = cs*scale, ci = sn*scale;
    float2 v = make_float2(sr*cr - si*ci, sr*ci + si*cr);
    g_Mf[tid] = v;
    g_MfT[(m<<7) + o] = v;
    int p = (o*m) & 127;
    float ang2 = TWO_PI_F*(float)p/128.0f;
    float sn2, cs2; __sincosf(ang2, &sn2, &cs2);
    g_F[tid]  = make_float2(cs2, -sn2);
    g_IF[tid] = make_float2(cs2*0.0078125f, sn2*0.0078125f);
}

// ---------------- stream loaders (rmul T-side, LM2/3 staging) ----------------
template<int LM>
__device__ inline void load_T4(float2* tr, const float* mp, const float* pp,
                               const float* Trl, int hh, int w4) {
    if (LM == 2) {
#pragma unroll
        for (int i = 0; i < 4; ++i) {
            int idx = (hh<<7) + w4 + i;
            float m = mp[idx], ph = pp[idx];
            float sn, cs; __sincosf(ph, &sn, &cs);
            tr[i] = make_float2(m*cs, m*sn);
        }
    } else {
#pragma unroll
        for (int i = 0; i < 4; ++i) {
            int w = w4 + i;
            int h2 = hh, w2 = w; float sg = 1.f;
            if (w >= 65) { h2 = (128 - hh) & 127; w2 = 128 - w; sg = -1.f; }
            int idx = h2*65 + w2;
            float m = mp[idx], ph = pp[idx];
            float sn, cs; __sincosf(ph, &sn, &cs);
            tr[i] = make_float2(m*cs, sg*m*sn);
        }
    }
}

__device__ inline void cfma(float2& a, float sx, float sy, float mx, float my) {
    a.x = fmaf(sx, mx, a.x); a.x = fmaf(-sy, my, a.x);
    a.y = fmaf(sx, my, a.y); a.y = fmaf(sy, mx, a.y);
}

// ---------------- rmul body (stages 2/5): out[p,h,j] = sum_w T*A ------------
// Round-5 proven form. LM1: stream rows via wave-uniform global reads, m-side
// direct global, zero barriers. LM2/3: stream via sincos into Ssh (1 barrier).
template<int LM>
__device__ inline void rmul_body(const float2* __restrict__ MT, const float* __restrict__ Trl,
                                 const float* __restrict__ mp_, const float* __restrict__ pp_,
                                 float2* __restrict__ out, int cstart,
                                 int p, int r0, int t, float2* Ssh) {
    constexpr bool RS = (LM == 1);
    const float* Trp = nullptr; const float* mp = nullptr; const float* pp = nullptr;
    if (LM == 1) { int n = p >> 4, c = p & 15; Trp = Trl + ((long)(n*48 + cstart + c) << 14); }
    if (LM == 2) { mp = mp_ + ((long)p << 14); pp = pp_ + ((long)p << 14); }
    if (LM == 3) { mp = mp_ + (long)p*8320;   pp = pp_ + (long)p*8320; }
    int cq = t & 63, rp = t >> 6;
    const float* Tr_row[4];
    if (RS) {
#pragma unroll
        for (int i = 0; i < 4; ++i) {
            int ro = __builtin_amdgcn_readfirstlane((r0 + (rp<<2) + i) << 7);
            Tr_row[i] = Trp + ro;
        }
    } else {
        for (int u = t; u < 512; u += 256) {
            int row = u >> 5, w4 = (u & 31) << 2;
            float2 tr4[4];
            load_T4<LM>(tr4, mp, pp, Trp, r0 + row, w4);
            float4* d = (float4*)&Ssh[(row << 7) + w4];
            d[0] = make_float4(tr4[0].x, tr4[0].y, tr4[1].x, tr4[1].y);
            d[1] = make_float4(tr4[2].x, tr4[2].y, tr4[3].x, tr4[3].y);
        }
        __syncthreads();
    }
    float2 acc[4][2] = {};
#pragma unroll 8
    for (int k2 = 0; k2 < 64; ++k2) {
        int k = k2 << 1;
        float4 m0 = *(const float4*)&MT[(k << 7) + (cq<<1)];
        float4 m1 = *(const float4*)&MT[((k+1) << 7) + (cq<<1)];
        if (RS) {
            float2 sr4[4];
#pragma unroll
            for (int i = 0; i < 4; ++i)
                sr4[i] = *(const float2*)(Tr_row[i] + k);
#pragma unroll
            for (int i = 0; i < 4; ++i) {
                acc[i][0].x = fmaf(sr4[i].x, m0.x, acc[i][0].x);
                acc[i][0].y = fmaf(sr4[i].x, m0.y, acc[i][0].y);
                acc[i][1].x = fmaf(sr4[i].x, m0.z, acc[i][1].x);
                acc[i][1].y = fmaf(sr4[i].x, m0.w, acc[i][1].y);
                acc[i][0].x = fmaf(sr4[i].y, m1.x, acc[i][0].x);
                acc[i][0].y = fmaf(sr4[i].y, m1.y, acc[i][0].y);
                acc[i][1].x = fmaf(sr4[i].y, m1.z, acc[i][1].x);
                acc[i][1].y = fmaf(sr4[i].y, m1.w, acc[i][1].y);
            }
        } else {
            float4 s2[4];
#pragma unroll
            for (int i = 0; i < 4; ++i)
                s2[i] = *(const float4*)&Ssh[(((rp<<2)+i) << 7) + k];
#pragma unroll
            for (int i = 0; i < 4; ++i) {
                cfma(acc[i][0], s2[i].x, s2[i].y, m0.x, m0.y);
                cfma(acc[i][1], s2[i].x, s2[i].y, m0.z, m0.w);
                cfma(acc[i][0], s2[i].z, s2[i].w, m1.x, m1.y);
                cfma(acc[i][1], s2[i].z, s2[i].w, m1.z, m1.w);
            }
        }
    }
    long base = ((long)p << 14);
#pragma unroll
    for (int i = 0; i < 4; ++i) {
        float4* dst = (float4*)(out + base + ((long)(r0 + (rp<<2) + i) << 7) + (cq<<1));
        *dst = make_float4(acc[i][0].x, acc[i][0].y, acc[i][1].x, acc[i][1].y);
    }
}

// ---------------- lmul (stages 3/6): 1-wave blocks, 8 rows/thread ------------
// out[p,j,w] = sum_h A[j,h] * T[p,h,w]. Block = 64 threads = 1 wave; covers
// 8 j-rows x 128 w. grid (128,16) -> 2048 blocks = 8 waves/CU. m-side bytes
// per FMA halved vs 4-row (2KB/wave feeds 128 FMA insts = 8 B/cyc/wave;
// 8 waves/CU = 64 B/cyc ~= L1 supply -> VALU-bound). A-rows via wave-uniform
// scalar loads. Zero LDS, zero barriers.
// EPI 1: mag/pha  2: abs->cat  3: real->cat  4: packed65
template<int EPI>
__device__ inline void lmul_body64(const float2* __restrict__ A, const float2* __restrict__ in,
                                   float* __restrict__ o1, float* __restrict__ o2, int coff,
                                   int p, int j0, int t) {
    const float2* T = in + ((long)p << 14);
    const float2* Arow[8];
#pragma unroll
    for (int i = 0; i < 8; ++i) {
        int ro = __builtin_amdgcn_readfirstlane((j0 + i) << 7);
        Arow[i] = A + ro;
    }
    const float2* Tc = T + (t << 1);
    float2 acc[8][2] = {};
#pragma unroll 4
    for (int k2 = 0; k2 < 64; ++k2) {
        int k = k2 << 1;
        float4 m0 = *(const float4*)&Tc[(k  ) << 7];
        float4 m1 = *(const float4*)&Tc[(k+1) << 7];
        float4 s2[8];
#pragma unroll
        for (int i = 0; i < 8; ++i)
            s2[i] = *(const float4*)(Arow[i] + k);
#pragma unroll
        for (int i = 0; i < 8; ++i) {
            if (EPI == 3) {
                acc[i][0].x = fmaf(s2[i].x, m0.x, acc[i][0].x);
                acc[i][0].x = fmaf(-s2[i].y, m0.y, acc[i][0].x);
                acc[i][1].x = fmaf(s2[i].x, m0.z, acc[i][1].x);
                acc[i][1].x = fmaf(-s2[i].y, m0.w, acc[i][1].x);
                acc[i][0].x = fmaf(s2[i].z, m1.x, acc[i][0].x);
                acc[i][0].x = fmaf(-s2[i].w, m1.y, acc[i][0].x);
                acc[i][1].x = fmaf(s2[i].z, m1.z, acc[i][1].x);
                acc[i][1].x = fmaf(-s2[i].w, m1.w, acc[i][1].x);
            } else {
                cfma(acc[i][0], s2[i].x, s2[i].y, m0.x, m0.y);
                cfma(acc[i][1], s2[i].x, s2[i].y, m0.z, m0.w);
                cfma(acc[i][0], s2[i].z, s2[i].w, m1.x, m1.y);
                cfma(acc[i][1], s2[i].z, s2[i].w, m1.z, m1.w);
            }
        }
    }
#pragma unroll
    for (int i = 0; i < 8; ++i) {
        int jj = j0 + i;
        int ww0 = t << 1;
        float2 v0 = acc[i][0], v1 = acc[i][1];
        if (EPI == 1) {
            long idx = ((long)p << 14) + ((long)jj << 7) + ww0;
            *(float2*)&o1[idx] = make_float2(sqrtf(v0.x*v0.x + v0.y*v0.y),
                                             sqrtf(v1.x*v1.x + v1.y*v1.y));
            *(float2*)&o2[idx] = make_float2(atan2f(v0.y, v0.x), atan2f(v1.y, v1.x));
        } else if (EPI == 2) {
            int n = p >> 4, c = p & 15;
            long idx = ((long)(n*48 + coff + c) << 14) + ((long)jj << 7) + ww0;
            *(float2*)&o1[idx] = make_float2(sqrtf(v0.x*v0.x + v0.y*v0.y),
                                             sqrtf(v1.x*v1.x + v1.y*v1.y));
        } else if (EPI == 3) {
            int n = p >> 4, c = p & 15;
            long idx = ((long)(n*48 + coff + c) << 14) + ((long)jj << 7) + ww0;
            *(float2*)&o1[idx] = make_float2(v0.x, v1.x);
        } else if (EPI == 4) {
            if (ww0 < 65) {
                long idx = (long)p*8320 + jj*65 + ww0;
                o1[idx] = sqrtf(v0.x*v0.x + v0.y*v0.y);
                o2[idx] = atan2f(v0.y, v0.x);
                if (ww0 + 1 < 65) {
                    o1[idx+1] = sqrtf(v1.x*v1.x + v1.y*v1.y);
                    o2[idx+1] = atan2f(v1.y, v1.x);
                }
            }
        }
    }
}

// ---------------- dual rmul kernel (+ Mb build at bx>=128) -------------------
// grid (136, 8): bx<128 -> plane (A: 0..63, B: 64..127), by = strip.
// id % 8 == bx % 8 -> all strips of a plane land on one XCD.
template<int LMA, int LMB>
__global__ __launch_bounds__(256, 4)
void k_rmul_dual(const float2* __restrict__ MTa, const float* __restrict__ TrlA,
                 const float* __restrict__ mpA, const float* __restrict__ ppA,
                 float2* __restrict__ outA, int cstartA,
                 const float2* __restrict__ MTb, const float* __restrict__ TrlB,
                 const float* __restrict__ mpB, const float* __restrict__ ppB,
                 float2* __restrict__ outB, int cstartB) {
    __shared__ __align__(16) float2 Ssh[(LMA == 1 && LMB == 1) ? 2 : 16*128];
    __shared__ float2 W[128];
    int bx = blockIdx.x, by = blockIdx.y, t = threadIdx.x;
    if (bx >= 128) {
        int b = (bx - 128)*8 + by;
        if (b < 64) {
            if (t < 128) {
                float ang = TWO_PI_F*(float)t/128.0f;
                float sn, cs; __sincosf(ang, &sn, &cs);
                float invs = 0.08838834764831845f;
                W[t] = make_float2(cs*invs, sn*invs);
            }
            __syncthreads();
            int tid = b*256 + t;
            int o = tid >> 7, m = tid & 127;
            float sr = 0.f, si = 0.f;
            for (int r = 0; r < 128; ++r) {
                float2 a = g_Mf[(o<<7) + r];
                int k = ((r+64)*(m+64)) & 127;
                float2 w = W[k];
                sr += a.x*w.x - a.y*w.y;
                si += a.x*w.y + a.y*w.x;
            }
            float2 v = make_float2(sr, si);
            g_Mb[tid] = v;
            g_MbT[(m<<7) + o] = v;
        }
        return;
    }
    int p = bx & 63, r0 = by << 4;
    if (bx < 64) rmul_body<LMA>(MTa, TrlA, mpA, ppA, outA, cstartA, p, r0, t, Ssh);
    else         rmul_body<LMB>(MTb, TrlB, mpB, ppB, outB, cstartB, p, r0, t, Ssh);
}

// ---------------- dual lmul kernel (1-wave blocks, XCD-pinned planes) --------
template<int EPIA, int EPIB>
__global__ __launch_bounds__(64, 2)
void k_lmul_dual(const float2* __restrict__ Aa, const float2* __restrict__ inA,
                 float* __restrict__ o1A, float* __restrict__ o2A, int coffA,
                 const float2* __restrict__ Ab, const float2* __restrict__ inB,
                 float* __restrict__ o1B, float* __restrict__ o2B, int coffB) {
    int bx = blockIdx.x, j0 = blockIdx.y << 3, t = threadIdx.x;
    int p = bx & 63;
    if (bx < 64) lmul_body64<EPIA>(Aa, inA, o1A, o2A, coffA, p, j0, t);
    else         lmul_body64<EPIB>(Ab, inB, o1B, o2B, coffB, p, j0, t);
}

// ---------------- wave-level 1x1 conv body -----------------------------------
template<int CIN, int COUT, int KSPLIT, int OSPLIT>
__device__ inline void wconv_body(const float* __restrict__ in, const float* __restrict__ wgt,
                                  const float* __restrict__ bias, float* __restrict__ out,
                                  int S, int Ctin, int cstart, int Ctout, int costart,
                                  int n, int sblk, float* red) {
    constexpr int OW = COUT / OSPLIT;
    constexpr int KC = CIN / KSPLIT;
    int t = threadIdx.x, lane = t & 63;
    int wv = __builtin_amdgcn_readfirstlane(t >> 6);
    int oq = wv / KSPLIT, kq = wv % KSPLIT;
    int s0 = sblk << 7;
    const float* inb = in + ((long)(n*Ctin + cstart + kq*KC))*S + s0 + (lane<<1);
    const float* wb  = wgt + (oq*OW)*CIN + kq*KC;
    float2 acc[OW];
#pragma unroll
    for (int j = 0; j < OW; ++j) acc[j] = make_float2(0.f, 0.f);
#pragma unroll 4
    for (int c = 0; c < KC; ++c) {
        float2 xv = *(const float2*)(inb + (long)c*S);
#pragma unroll
        for (int j = 0; j < OW; ++j) {
            float w = wb[j*CIN + c];
            acc[j].x = fmaf(w, xv.x, acc[j].x);
            acc[j].y = fmaf(w, xv.y, acc[j].y);
        }
    }
    if (KSPLIT == 1) {
#pragma unroll
        for (int j = 0; j < OW; ++j) {
            int o = oq*OW + j;
            float b = bias ? bias[o] : 0.f;
            *(float2*)(out + ((long)(n*Ctout + costart + o))*S + s0 + (lane<<1))
                = make_float2(acc[j].x + b, acc[j].y + b);
        }
    } else {
#pragma unroll
        for (int j = 0; j < OW; ++j) {
            int o = oq*OW + j;
            *(float2*)&red[((kq*COUT + o) << 7) + (lane<<1)] = acc[j];
        }
        __syncthreads();
        for (int idx = t; idx < COUT*64; idx += 256) {
            int o = idx >> 6, l2 = (idx & 63) << 1;
            float b = bias ? bias[o] : 0.f;
            float2 v = make_float2(b, b);
#pragma unroll
            for (int k2 = 0; k2 < KSPLIT; ++k2) {
                float2 r = *(const float2*)&red[((k2*COUT + o) << 7) + l2];
                v.x += r.x; v.y += r.y;
            }
            *(float2*)(out + ((long)(n*Ctout + costart + o))*S + s0 + l2) = v;
        }
    }
}

// ---------------- stage 1: conv1 + matrix builder ----------------------------
__global__ __launch_bounds__(256, 1)
void k_conv1_build(const float* __restrict__ x, const float* __restrict__ w,
                   float* __restrict__ x1) {
    __shared__ float red[2*48*128];
    if (blockIdx.z == 0) {
        wconv_body<192,48,2,2>(x, w, nullptr, x1, 16384, 192, 0, 48, 0,
                               blockIdx.y, blockIdx.x, red);
    } else {
        int b = blockIdx.y*gridDim.x + blockIdx.x;
        if (b < 64) build_A_body(b*256 + threadIdx.x);
    }
}

// ---------------- stage 7: conv2 ---------------------------------------------
__global__ __launch_bounds__(256, 1)
void k_conv2(const float* __restrict__ in, const float* __restrict__ wgt,
             float* __restrict__ out) {
    __shared__ float red[1];
    wconv_body<48,192,1,4>(in, wgt, nullptr, out, 16384, 48, 0, 192, 0,
                           blockIdx.y, blockIdx.x, red);
}

// ---------------- pointwise stage: maskconv + 4 channel-mixes ----------------
__device__ inline void mix16b(const float* __restrict__ in, const float* __restrict__ w,
                              const float* __restrict__ b, float* __restrict__ out,
                              int Ctin, int S, int n, int s0base, int Slim) {
    int t = threadIdx.x, lane = t & 63;
    int wv = __builtin_amdgcn_readfirstlane(t >> 6);
    int oq = wv & 3, pg = wv >> 2;
    int s0 = s0base + (pg << 7);
    if (s0 >= Slim) return;                    // no __syncthreads in this path
    const float* inb = in + ((long)(n*Ctin))*S + s0 + (lane<<1);
    float2 acc[4];
#pragma unroll
    for (int j = 0; j < 4; ++j) {
        float bb = b ? b[oq*4 + j] : 0.f;
        acc[j] = make_float2(bb, bb);
    }
#pragma unroll
    for (int half = 0; half < 2; ++half) {
        float2 xv[8];
#pragma unroll
        for (int c = 0; c < 8; ++c)
            xv[c] = *(const float2*)(inb + (long)(half*8 + c)*S);
#pragma unroll
        for (int c = 0; c < 8; ++c) {
#pragma unroll
            for (int j = 0; j < 4; ++j) {
                float ww = w[(oq*4 + j)*16 + half*8 + c];
                acc[j].x = fmaf(ww, xv[c].x, acc[j].x);
                acc[j].y = fmaf(ww, xv[c].y, acc[j].y);
            }
        }
    }
#pragma unroll
    for (int j = 0; j < 4; ++j) {
        int o = oq*4 + j;
        *(float2*)(out + ((long)(n*Ctin + o))*S + s0 + (lane<<1)) = acc[j];
    }
}

__device__ inline void maskconv_body(const float* __restrict__ mag, const float* __restrict__ ws3,
                                     const float* __restrict__ bs, const float* __restrict__ wf,
                                     const float* __restrict__ bf, const float* __restrict__ wm,
                                     const float* __restrict__ bm, float* __restrict__ out,
                                     int n, int tile, float* patch) {
    int h0 = (tile >> 3) << 4, w0 = (tile & 7) << 4;
    int t = threadIdx.x;
    const float* magn = mag + ((long)n << 18);
    for (int idx = t; idx < 16*324; idx += 1024) {
        int c = idx / 324, r = idx - c*324;
        int ph = r / 18, pw = r - ph*18;
        int gh = h0 - 1 + ph, gw = w0 - 1 + pw;
        float v = 0.f;
        if (gh >= 19 && gh < 109 && gw >= 19 && gw < 109)
            v = magn[(c<<14) + (gh<<7) + gw];
        patch[c*324 + r] = v;
    }
    __syncthreads();
    int oq = t >> 8, pix = t & 255;
    int ty = pix >> 4, tx = pix & 15;
    int h = h0 + ty, w = w0 + tx;
    bool in1 = (h >= 19 && h < 109 && w >= 19 && w < 109);
    unsigned long long bal = __ballot(in1);
    float res[4];
    if (bal != 0ull) {
        float acc[4];
#pragma unroll
        for (int j = 0; j < 4; ++j) acc[j] = bs[oq*4 + j];
        for (int c = 0; c < 16; ++c) {
            const float* pc = patch + c*324 + ty*18 + tx;
            const float* wc = ws3 + c*9;
#pragma unroll
            for (int dh = 0; dh < 3; ++dh) {
#pragma unroll
                for (int dw = 0; dw < 3; ++dw) {
                    float tap = pc[dh*18 + dw];
#pragma unroll
                    for (int j = 0; j < 4; ++j)
                        acc[j] = fmaf(wc[(oq*4 + j)*144 + dh*3 + dw], tap, acc[j]);
                }
            }
        }
#pragma unroll
        for (int j = 0; j < 4; ++j) res[j] = acc[j];
    }
    if (bal != ~0ull) {
        float acc2[4];
#pragma unroll
        for (int j = 0; j < 4; ++j) acc2[j] = bf[oq*4 + j];
#pragma unroll
        for (int half = 0; half < 2; ++half) {
            float xv[8];
#pragma unroll
            for (int c = 0; c < 8; ++c)
                xv[c] = magn[((half*8 + c)<<14) + (h<<7) + w];
#pragma unroll
            for (int c = 0; c < 8; ++c)
#pragma unroll
                for (int j = 0; j < 4; ++j)
                    acc2[j] = fmaf(wf[(oq*4 + j)*16 + half*8 + c], xv[c], acc2[j]);
        }
        if (!in1) {
#pragma unroll
            for (int j = 0; j < 4; ++j) res[j] = acc2[j];
        }
    }
    __syncthreads();               // all reads of patch complete
    float* resl = patch;           // reuse as [16][256]
#pragma unroll
    for (int j = 0; j < 4; ++j) resl[(oq*4 + j)*256 + pix] = res[j];
    __syncthreads();
    float rr[16];
#pragma unroll
    for (int o = 0; o < 16; ++o) rr[o] = resl[o*256 + pix];
#pragma unroll
    for (int j = 0; j < 4; ++j) {
        int o2 = oq*4 + j;
        float a = bm[o2];
#pragma unroll
        for (int o = 0; o < 16; ++o)
            a = fmaf(wm[o2*16 + o], rr[o], a);
        out[((long)((n<<4) + o2) << 14) + (h << 7) + w] = a;
    }
}

__global__ __launch_bounds__(1024, 8)
void k_point(const float* __restrict__ mag, const float* __restrict__ ws3,
             const float* __restrict__ bs, const float* __restrict__ wf,
             const float* __restrict__ bf, const float* __restrict__ wm,
             const float* __restrict__ bm, float* __restrict__ t2,
             const float* __restrict__ pha, const float* __restrict__ pw,
             const float* __restrict__ pb, float* __restrict__ t1,
             const float* __restrict__ x1, const float* __restrict__ c0w,
             const float* __restrict__ c0b, float* __restrict__ cat,
             const float* __restrict__ m65, const float* __restrict__ p65,
             const float* __restrict__ c1w, const float* __restrict__ c1b,
             float* __restrict__ t3, float* __restrict__ t4) {
    __shared__ float patch[16*324];
    int b = blockIdx.x;
    if (b < 256) {
        maskconv_body(mag, ws3, bs, wf, bf, wm, bm, t2, b >> 6, b & 63, patch);
    } else if (b < 384) {
        int i = b - 256;               // pha channel-mix (S=16384): 32 blocks/n
        mix16b(pha, pw, pb, t1, 16, 16384, i >> 5, (i & 31) << 9, 16384);
    } else if (b < 512) {
        int i = b - 384;               // conv_0: x1 ch0..15 -> cat ch0..15 (Ct=48)
        mix16b(x1, c0w, c0b, cat, 48, 16384, i >> 5, (i & 31) << 9, 16384);
    } else if (b < 580) {
        int i = b - 512;               // m65 mix (S=8320): 17 blocks/n
        mix16b(m65, c1w, c1b, t3, 16, 8320, i / 17, (i % 17) << 9, 8320);
    } else {
        int i = b - 580;               // p65 mix
        mix16b(p65, c1w, c1b, t4, 16, 8320, i / 17, (i % 17) << 9, 8320);
    }
}

// ---------------- launch ----------------------------------------------------
extern "C" void kernel_launch(void* const* d_in, const int* in_sizes, int n_in,
                              void* d_out, int out_size, void* d_ws, size_t ws_size,
                              hipStream_t stream) {
    (void)in_sizes; (void)n_in; (void)out_size; (void)d_ws; (void)ws_size;
    const float* x        = (const float*)d_in[0];
    const float* conv1_w  = (const float*)d_in[1];
    const float* mag_s_w  = (const float*)d_in[2];
    const float* mag_s_b  = (const float*)d_in[3];
    const float* mag_f_w  = (const float*)d_in[4];
    const float* mag_f_b  = (const float*)d_in[5];
    const float* mag_w_   = (const float*)d_in[6];
    const float* mag_b_   = (const float*)d_in[7];
    const float* pha_w_   = (const float*)d_in[8];
    const float* pha_b_   = (const float*)d_in[9];
    const float* conv_0_w = (const float*)d_in[10];
    const float* conv_0_b = (const float*)d_in[11];
    const float* conv_1_w = (const float*)d_in[12];
    const float* conv_1_b = (const float*)d_in[13];
    const float* conv2_w  = (const float*)d_in[14];
    float* outp = (float*)d_out;

    float2 *Mf, *MfT, *Mb, *MbT, *Fm, *IFm, *bufA, *bufB;
    float *x1, *mag, *pha, *m65, *p65, *t1, *t2, *t3, *t4, *cat;
    hipGetSymbolAddress((void**)&Mf,   HIP_SYMBOL(g_Mf));
    hipGetSymbolAddress((void**)&MfT,  HIP_SYMBOL(g_MfT));
    hipGetSymbolAddress((void**)&Mb,   HIP_SYMBOL(g_Mb));
    hipGetSymbolAddress((void**)&MbT,  HIP_SYMBOL(g_MbT));
    hipGetSymbolAddress((void**)&Fm,   HIP_SYMBOL(g_F));
    hipGetSymbolAddress((void**)&IFm,  HIP_SYMBOL(g_IF));
    hipGetSymbolAddress((void**)&bufA, HIP_SYMBOL(g_bufA));
    hipGetSymbolAddress((void**)&bufB, HIP_SYMBOL(g_bufB));
    hipGetSymbolAddress((void**)&x1,   HIP_SYMBOL(g_x1));
    hipGetSymbolAddress((void**)&mag,  HIP_SYMBOL(g_mag));
    hipGetSymbolAddress((void**)&pha,  HIP_SYMBOL(g_pha));
    hipGetSymbolAddress((void**)&m65,  HIP_SYMBOL(g_m65));
    hipGetSymbolAddress((void**)&p65,  HIP_SYMBOL(g_p65));
    hipGetSymbolAddress((void**)&t1,   HIP_SYMBOL(g_t1));
    hipGetSymbolAddress((void**)&t2,   HIP_SYMBOL(g_t2));
    hipGetSymbolAddress((void**)&t3,   HIP_SYMBOL(g_t3));
    hipGetSymbolAddress((void**)&t4,   HIP_SYMBOL(g_t4));
    hipGetSymbolAddress((void**)&cat,  HIP_SYMBOL(g_cat));

    dim3 bt(256, 1, 1);
    dim3 bt64(64, 1, 1);

    // stage 1: conv1 (x -> x1) + build Mf/MfT/F/IF
    k_conv1_build<<<dim3(128,4,2), bt, 0, stream>>>(x, conv1_w, x1);

    // stage 2: dual rmul (FRFT fwd -> bufA; FFT fwd -> bufB) + build Mb
    k_rmul_dual<1,1><<<dim3(136,8), bt, 0, stream>>>(
        MfT, x1, nullptr, nullptr, bufA, 16,
        Fm,  x1, nullptr, nullptr, bufB, 32);

    // stage 3: dual lmul (mag/pha full <- bufA; packed65 <- bufB)
    k_lmul_dual<1,4><<<dim3(128,16), bt64, 0, stream>>>(
        Mf, bufA, mag, pha, 0,
        Fm, bufB, m65, p65, 0);

    // stage 4: maskconv(+mag mix) | pha mix | conv_0 | m65 mix | p65 mix
    k_point<<<648, dim3(1024,1,1), 0, stream>>>(mag, mag_s_w, mag_s_b, mag_f_w, mag_f_b,
                                                mag_w_, mag_b_, t2,
                                                pha, pha_w_, pha_b_, t1,
                                                x1, conv_0_w, conv_0_b, cat,
                                                m65, p65, conv_1_w, conv_1_b, t3, t4);

    // stage 5: dual rmul (FRFT bwd combine(t2,t1) -> bufA; irfft combine65(t3,t4) -> bufB)
    k_rmul_dual<2,3><<<dim3(128,8), bt, 0, stream>>>(
        MbT, nullptr, t2, t1, bufA, 0,
        IFm, nullptr, t3, t4, bufB, 0);

    // stage 6: dual lmul (abs -> cat ch16..31; real -> cat ch32..47)
    k_lmul_dual<2,3><<<dim3(128,16), bt64, 0, stream>>>(
        Mb,  bufA, cat, nullptr, 16,
        IFm, bufB, cat, nullptr, 32);

    // stage 7: conv2 (cat -> out)
    k_conv2<<<dim3(128,4), bt, 0, stream>>>(cat, conv2_w, outp);
}

// Round 12
// 313.563 us; speedup vs baseline: 1.0646x; 1.0442x over previous
//
#include <hip/hip_runtime.h>
#include <math.h>

#define PI_D 3.14159265358979323846
#define TWO_PI_F 6.2831853071795864f

// ---------------- persistent device buffers ---------------------------------
__device__ __align__(16) float2 g_Mf [128*128];
__device__ __align__(16) float2 g_MfT[128*128];
__device__ __align__(16) float2 g_Mb [128*128];
__device__ __align__(16) float2 g_MbT[128*128];
__device__ __align__(16) float2 g_F  [128*128];   // symmetric
__device__ __align__(16) float2 g_IF [128*128];   // symmetric
__device__ __align__(16) float  g_x1 [4*48*16384];
__device__ __align__(16) float2 g_bufA[64*16384];
__device__ __align__(16) float2 g_bufB[64*16384];
__device__ __align__(16) float  g_mag[64*16384];
__device__ __align__(16) float  g_pha[64*16384];
__device__ __align__(16) float  g_m65[64*8320];
__device__ __align__(16) float  g_p65[64*8320];
__device__ __align__(16) float  g_t1 [64*16384];
__device__ __align__(16) float  g_t2 [64*16384];
__device__ __align__(16) float  g_t3 [64*8320];
__device__ __align__(16) float  g_t4 [64*8320];
__device__ __align__(16) float  g_cat[4*48*16384];

// ---------------- builder body -----------------------------------------------
__device__ inline void build_A_body(int tid) {
    if (tid >= 128*128) return;
    int o = tid >> 7, m = tid & 127;
    const double chc = -PI_D/128.0 * tan(PI_D/8.0) * 0.25;
    const double c   =  PI_D/(512.0*sin(PI_D/4.0));
    const double inv2pi = 1.0/(2.0*PI_D);
    float sr, si;
    {   // q = 2m term (sinc = 1)
        int n1 = 2*m - 127, tt = 2*(o - m);
        double ang = chc*(double)(n1*n1) + c*(double)(tt*tt);
        double r = ang*inv2pi; r -= floor(r);
        float af = (float)(r*2.0*PI_D);
        float sn, cs; __sincosf(af, &sn, &cs);
        sr = cs; si = sn;
    }
    for (int j = 0; j < 127; ++j) {
        int q  = 2*j + 1;
        int n1 = q - 127, tt = 2*o - q, d = q - 2*m;
        double ang = chc*(double)(n1*n1) + c*(double)(tt*tt);
        double r = ang*inv2pi; r -= floor(r);
        float af = (float)(r*2.0*PI_D);
        float s = (((d-1)>>1) & 1) ? -2.0f : 2.0f;
        s /= (3.14159265358979f*(float)d);
        float sn, cs; __sincosf(af, &sn, &cs);
        sr += s*cs; si += s*sn;
    }
    int n2 = 2*o - 127;
    double ph = chc*(double)(n2*n2) - PI_D/8.0;
    double r = ph*inv2pi; r -= floor(r);
    float pf = (float)(r*2.0*PI_D);
    float scale = (float)sqrt(c/PI_D);
    float sn, cs; __sincosf(pf, &sn, &cs);
    float cr = cs*scale, ci = sn*scale;
    float2 v = make_float2(sr*cr - si*ci, sr*ci + si*cr);
    g_Mf[tid] = v;
    g_MfT[(m<<7) + o] = v;
    int p = (o*m) & 127;
    float ang2 = TWO_PI_F*(float)p/128.0f;
    float sn2, cs2; __sincosf(ang2, &sn2, &cs2);
    g_F[tid]  = make_float2(cs2, -sn2);
    g_IF[tid] = make_float2(cs2*0.0078125f, sn2*0.0078125f);
}

// ---------------- stream loaders (rmul T-side, LM2/3 staging) ----------------
template<int LM>
__device__ inline void load_T4(float2* tr, const float* mp, const float* pp,
                               const float* Trl, int hh, int w4) {
    if (LM == 2) {
#pragma unroll
        for (int i = 0; i < 4; ++i) {
            int idx = (hh<<7) + w4 + i;
            float m = mp[idx], ph = pp[idx];
            float sn, cs; __sincosf(ph, &sn, &cs);
            tr[i] = make_float2(m*cs, m*sn);
        }
    } else {
#pragma unroll
        for (int i = 0; i < 4; ++i) {
            int w = w4 + i;
            int h2 = hh, w2 = w; float sg = 1.f;
            if (w >= 65) { h2 = (128 - hh) & 127; w2 = 128 - w; sg = -1.f; }
            int idx = h2*65 + w2;
            float m = mp[idx], ph = pp[idx];
            float sn, cs; __sincosf(ph, &sn, &cs);
            tr[i] = make_float2(m*cs, sg*m*sn);
        }
    }
}

__device__ inline void cfma(float2& a, float sx, float sy, float mx, float my) {
    a.x = fmaf(sx, mx, a.x); a.x = fmaf(-sy, my, a.x);
    a.y = fmaf(sx, my, a.y); a.y = fmaf(sy, mx, a.y);
}

// ---------------- rmul body (round-5 proven form) ----------------------------
// LM1: stream rows via wave-uniform global reads, m-side direct global, zero
// barriers. LM2/3: stream via sincos into Ssh once (one barrier), then read.
template<int LM>
__device__ inline void rmul_body(const float2* __restrict__ MT, const float* __restrict__ Trl,
                                 const float* __restrict__ mp_, const float* __restrict__ pp_,
                                 float2* __restrict__ out, int cstart,
                                 int p, int r0, int t, float2* Ssh) {
    constexpr bool RS = (LM == 1);
    const float* Trp = nullptr; const float* mp = nullptr; const float* pp = nullptr;
    if (LM == 1) { int n = p >> 4, c = p & 15; Trp = Trl + ((long)(n*48 + cstart + c) << 14); }
    if (LM == 2) { mp = mp_ + ((long)p << 14); pp = pp_ + ((long)p << 14); }
    if (LM == 3) { mp = mp_ + (long)p*8320;   pp = pp_ + (long)p*8320; }
    int cq = t & 63, rp = t >> 6;
    const float* Tr_row[4];
    if (RS) {
#pragma unroll
        for (int i = 0; i < 4; ++i) {
            int ro = __builtin_amdgcn_readfirstlane((r0 + (rp<<2) + i) << 7);
            Tr_row[i] = Trp + ro;
        }
    } else {
        for (int u = t; u < 512; u += 256) {
            int row = u >> 5, w4 = (u & 31) << 2;
            float2 tr4[4];
            load_T4<LM>(tr4, mp, pp, Trp, r0 + row, w4);
            float4* d = (float4*)&Ssh[(row << 7) + w4];
            d[0] = make_float4(tr4[0].x, tr4[0].y, tr4[1].x, tr4[1].y);
            d[1] = make_float4(tr4[2].x, tr4[2].y, tr4[3].x, tr4[3].y);
        }
        __syncthreads();
    }
    float2 acc[4][2] = {};
#pragma unroll 8
    for (int k2 = 0; k2 < 64; ++k2) {
        int k = k2 << 1;
        float4 m0 = *(const float4*)&MT[(k << 7) + (cq<<1)];
        float4 m1 = *(const float4*)&MT[((k+1) << 7) + (cq<<1)];
        if (RS) {
            float2 sr4[4];
#pragma unroll
            for (int i = 0; i < 4; ++i)
                sr4[i] = *(const float2*)(Tr_row[i] + k);
#pragma unroll
            for (int i = 0; i < 4; ++i) {
                acc[i][0].x = fmaf(sr4[i].x, m0.x, acc[i][0].x);
                acc[i][0].y = fmaf(sr4[i].x, m0.y, acc[i][0].y);
                acc[i][1].x = fmaf(sr4[i].x, m0.z, acc[i][1].x);
                acc[i][1].y = fmaf(sr4[i].x, m0.w, acc[i][1].y);
                acc[i][0].x = fmaf(sr4[i].y, m1.x, acc[i][0].x);
                acc[i][0].y = fmaf(sr4[i].y, m1.y, acc[i][0].y);
                acc[i][1].x = fmaf(sr4[i].y, m1.z, acc[i][1].x);
                acc[i][1].y = fmaf(sr4[i].y, m1.w, acc[i][1].y);
            }
        } else {
            float4 s2[4];
#pragma unroll
            for (int i = 0; i < 4; ++i)
                s2[i] = *(const float4*)&Ssh[(((rp<<2)+i) << 7) + k];
#pragma unroll
            for (int i = 0; i < 4; ++i) {
                cfma(acc[i][0], s2[i].x, s2[i].y, m0.x, m0.y);
                cfma(acc[i][1], s2[i].x, s2[i].y, m0.z, m0.w);
                cfma(acc[i][0], s2[i].z, s2[i].w, m1.x, m1.y);
                cfma(acc[i][1], s2[i].z, s2[i].w, m1.z, m1.w);
            }
        }
    }
    long base = ((long)p << 14);
#pragma unroll
    for (int i = 0; i < 4; ++i) {
        float4* dst = (float4*)(out + base + ((long)(r0 + (rp<<2) + i) << 7) + (cq<<1));
        *dst = make_float4(acc[i][0].x, acc[i][0].y, acc[i][1].x, acc[i][1].y);
    }
}

// ---------------- lmul body (round-5 proven form) ----------------------------
// A-side rows: wave-uniform global reads. T-side: direct global coalesced row
// reads. Zero LDS, zero barriers. EPI 1: mag/pha  2: abs->cat  3: real->cat
// 4: packed65
template<int EPI>
__device__ inline void lmul_body(const float2* __restrict__ A, const float2* __restrict__ in,
                                 float* __restrict__ o1, float* __restrict__ o2, int coff,
                                 int p, int j0, int t) {
    const float2* T = in + ((long)p << 14);
    int cq = t & 63, rp = t >> 6;
    const float2* Arow[4];
#pragma unroll
    for (int i = 0; i < 4; ++i) {
        int ro = __builtin_amdgcn_readfirstlane((j0 + (rp<<2) + i) << 7);
        Arow[i] = A + ro;
    }
    float2 acc[4][2] = {};
#pragma unroll 8
    for (int k2 = 0; k2 < 64; ++k2) {
        int k = k2 << 1;
        float4 m0 = *(const float4*)&T[(k << 7) + (cq<<1)];
        float4 m1 = *(const float4*)&T[((k+1) << 7) + (cq<<1)];
        float4 s2[4];
#pragma unroll
        for (int i = 0; i < 4; ++i)
            s2[i] = *(const float4*)(Arow[i] + k);
#pragma unroll
        for (int i = 0; i < 4; ++i) {
            if (EPI == 3) {
                acc[i][0].x = fmaf(s2[i].x, m0.x, acc[i][0].x);
                acc[i][0].x = fmaf(-s2[i].y, m0.y, acc[i][0].x);
                acc[i][1].x = fmaf(s2[i].x, m0.z, acc[i][1].x);
                acc[i][1].x = fmaf(-s2[i].y, m0.w, acc[i][1].x);
                acc[i][0].x = fmaf(s2[i].z, m1.x, acc[i][0].x);
                acc[i][0].x = fmaf(-s2[i].w, m1.y, acc[i][0].x);
                acc[i][1].x = fmaf(s2[i].z, m1.z, acc[i][1].x);
                acc[i][1].x = fmaf(-s2[i].w, m1.w, acc[i][1].x);
            } else {
                cfma(acc[i][0], s2[i].x, s2[i].y, m0.x, m0.y);
                cfma(acc[i][1], s2[i].x, s2[i].y, m0.z, m0.w);
                cfma(acc[i][0], s2[i].z, s2[i].w, m1.x, m1.y);
                cfma(acc[i][1], s2[i].z, s2[i].w, m1.z, m1.w);
            }
        }
    }
#pragma unroll
    for (int i = 0; i < 4; ++i) {
        int jj = j0 + (rp<<2) + i;
        int ww0 = cq << 1;
        float2 v0 = acc[i][0], v1 = acc[i][1];
        if (EPI == 1) {
            long idx = ((long)p << 14) + ((long)jj << 7) + ww0;
            *(float2*)&o1[idx] = make_float2(sqrtf(v0.x*v0.x + v0.y*v0.y),
                                             sqrtf(v1.x*v1.x + v1.y*v1.y));
            *(float2*)&o2[idx] = make_float2(atan2f(v0.y, v0.x), atan2f(v1.y, v1.x));
        } else if (EPI == 2) {
            int n = p >> 4, c = p & 15;
            long idx = ((long)(n*48 + coff + c) << 14) + ((long)jj << 7) + ww0;
            *(float2*)&o1[idx] = make_float2(sqrtf(v0.x*v0.x + v0.y*v0.y),
                                             sqrtf(v1.x*v1.x + v1.y*v1.y));
        } else if (EPI == 3) {
            int n = p >> 4, c = p & 15;
            long idx = ((long)(n*48 + coff + c) << 14) + ((long)jj << 7) + ww0;
            *(float2*)&o1[idx] = make_float2(v0.x, v1.x);
        } else if (EPI == 4) {
            if (ww0 < 65) {
                long idx = (long)p*8320 + jj*65 + ww0;
                o1[idx] = sqrtf(v0.x*v0.x + v0.y*v0.y);
                o2[idx] = atan2f(v0.y, v0.x);
                if (ww0 + 1 < 65) {
                    o1[idx+1] = sqrtf(v1.x*v1.x + v1.y*v1.y);
                    o2[idx+1] = atan2f(v1.y, v1.x);
                }
            }
        }
    }
}

// ---------------- dual rmul kernel (+ Mb build at bx>=128) -------------------
// grid (136, 8): bx<128 -> plane (A: 0..63, B: 64..127), by = strip.
// id % 8 == bx % 8 -> all strips of a plane land on one XCD.
template<int LMA, int LMB>
__global__ __launch_bounds__(256, 4)
void k_rmul_dual(const float2* __restrict__ MTa, const float* __restrict__ TrlA,
                 const float* __restrict__ mpA, const float* __restrict__ ppA,
                 float2* __restrict__ outA, int cstartA,
                 const float2* __restrict__ MTb, const float* __restrict__ TrlB,
                 const float* __restrict__ mpB, const float* __restrict__ ppB,
                 float2* __restrict__ outB, int cstartB) {
    __shared__ __align__(16) float2 Ssh[(LMA == 1 && LMB == 1) ? 2 : 16*128];
    __shared__ float2 W[128];
    int bx = blockIdx.x, by = blockIdx.y, t = threadIdx.x;
    if (bx >= 128) {
        int b = (bx - 128)*8 + by;
        if (b < 64) {
            if (t < 128) {
                float ang = TWO_PI_F*(float)t/128.0f;
                float sn, cs; __sincosf(ang, &sn, &cs);
                float invs = 0.08838834764831845f;
                W[t] = make_float2(cs*invs, sn*invs);
            }
            __syncthreads();
            int tid = b*256 + t;
            int o = tid >> 7, m = tid & 127;
            float sr = 0.f, si = 0.f;
            for (int r = 0; r < 128; ++r) {
                float2 a = g_Mf[(o<<7) + r];
                int k = ((r+64)*(m+64)) & 127;
                float2 w = W[k];
                sr += a.x*w.x - a.y*w.y;
                si += a.x*w.y + a.y*w.x;
            }
            float2 v = make_float2(sr, si);
            g_Mb[tid] = v;
            g_MbT[(m<<7) + o] = v;
        }
        return;
    }
    int p = bx & 63, r0 = by << 4;
    if (bx < 64) rmul_body<LMA>(MTa, TrlA, mpA, ppA, outA, cstartA, p, r0, t, Ssh);
    else         rmul_body<LMB>(MTb, TrlB, mpB, ppB, outB, cstartB, p, r0, t, Ssh);
}

// ---------------- dual lmul kernel (XCD-pinned planes, no LDS) ---------------
template<int EPIA, int EPIB>
__global__ __launch_bounds__(256, 4)
void k_lmul_dual(const float2* __restrict__ Aa, const float2* __restrict__ inA,
                 float* __restrict__ o1A, float* __restrict__ o2A, int coffA,
                 const float2* __restrict__ Ab, const float2* __restrict__ inB,
                 float* __restrict__ o1B, float* __restrict__ o2B, int coffB) {
    int bx = blockIdx.x, j0 = blockIdx.y << 4, t = threadIdx.x;
    int p = bx & 63;
    if (bx < 64) lmul_body<EPIA>(Aa, inA, o1A, o2A, coffA, p, j0, t);
    else         lmul_body<EPIB>(Ab, inB, o1B, o2B, coffB, p, j0, t);
}

// ---------------- wave-level 1x1 conv body (KSPLIT=1, no LDS) -----------------
template<int CIN, int COUT, int OSPLIT>
__device__ inline void wconv_body(const float* __restrict__ in, const float* __restrict__ wgt,
                                  const float* __restrict__ bias, float* __restrict__ out,
                                  int S, int Ctin, int cstart, int Ctout, int costart,
                                  int n, int sblk) {
    constexpr int OW = COUT / OSPLIT;
    int t = threadIdx.x, lane = t & 63;
    int oq = __builtin_amdgcn_readfirstlane(t >> 6);
    int s0 = sblk << 7;
    const float* inb = in + ((long)(n*Ctin + cstart))*S + s0 + (lane<<1);
    const float* wb  = wgt + (oq*OW)*CIN;
    float2 acc[OW];
#pragma unroll
    for (int j = 0; j < OW; ++j) acc[j] = make_float2(0.f, 0.f);
#pragma unroll 4
    for (int c = 0; c < CIN; ++c) {
        float2 xv = *(const float2*)(inb + (long)c*S);
#pragma unroll
        for (int j = 0; j < OW; ++j) {
            float w = wb[j*CIN + c];
            acc[j].x = fmaf(w, xv.x, acc[j].x);
            acc[j].y = fmaf(w, xv.y, acc[j].y);
        }
    }
#pragma unroll
    for (int j = 0; j < OW; ++j) {
        int o = oq*OW + j;
        float b = bias ? bias[o] : 0.f;
        *(float2*)(out + ((long)(n*Ctout + costart + o))*S + s0 + (lane<<1))
            = make_float2(acc[j].x + b, acc[j].y + b);
    }
}

// ---------------- stage 1: conv1 + matrix builder ----------------------------
// conv1: KSPLIT=1, OSPLIT=4 -> 4 waves x 12 outputs, zero LDS, zero barriers.
__global__ __launch_bounds__(256, 4)
void k_conv1_build(const float* __restrict__ x, const float* __restrict__ w,
                   float* __restrict__ x1) {
    if (blockIdx.z == 0) {
        wconv_body<192,48,4>(x, w, nullptr, x1, 16384, 192, 0, 48, 0,
                             blockIdx.y, blockIdx.x);
    } else {
        int b = blockIdx.y*gridDim.x + blockIdx.x;
        if (b < 64) build_A_body(b*256 + threadIdx.x);
    }
}

// ---------------- stage 7: conv2 ---------------------------------------------
// grid (128,4,2): z selects 96-output half; 4 waves x 24 outputs each,
// KSPLIT=1, zero LDS, LB(256,4) -> 1024 blocks = 4 blocks/CU.
__global__ __launch_bounds__(256, 4)
void k_conv2(const float* __restrict__ in, const float* __restrict__ wgt,
             float* __restrict__ out) {
    int z = blockIdx.z;
    wconv_body<48,96,4>(in, wgt + z*96*48, nullptr, out, 16384, 48, 0, 192, z*96,
                        blockIdx.y, blockIdx.x);
}

// ---------------- pointwise stage: maskconv + 4 channel-mixes ----------------
__device__ inline void mix16b(const float* __restrict__ in, const float* __restrict__ w,
                              const float* __restrict__ b, float* __restrict__ out,
                              int Ctin, int S, int n, int s0base, int Slim) {
    int t = threadIdx.x, lane = t & 63;
    int wv = __builtin_amdgcn_readfirstlane(t >> 6);
    int oq = wv & 3, pg = wv >> 2;
    int s0 = s0base + (pg << 7);
    if (s0 >= Slim) return;                    // no __syncthreads in this path
    const float* inb = in + ((long)(n*Ctin))*S + s0 + (lane<<1);
    float2 acc[4];
#pragma unroll
    for (int j = 0; j < 4; ++j) {
        float bb = b ? b[oq*4 + j] : 0.f;
        acc[j] = make_float2(bb, bb);
    }
#pragma unroll
    for (int half = 0; half < 2; ++half) {
        float2 xv[8];
#pragma unroll
        for (int c = 0; c < 8; ++c)
            xv[c] = *(const float2*)(inb + (long)(half*8 + c)*S);
#pragma unroll
        for (int c = 0; c < 8; ++c) {
#pragma unroll
            for (int j = 0; j < 4; ++j) {
                float ww = w[(oq*4 + j)*16 + half*8 + c];
                acc[j].x = fmaf(ww, xv[c].x, acc[j].x);
                acc[j].y = fmaf(ww, xv[c].y, acc[j].y);
            }
        }
    }
#pragma unroll
    for (int j = 0; j < 4; ++j) {
        int o = oq*4 + j;
        *(float2*)(out + ((long)(n*Ctin + o))*S + s0 + (lane<<1)) = acc[j];
    }
}

__device__ inline void maskconv_body(const float* __restrict__ mag, const float* __restrict__ ws3,
                                     const float* __restrict__ bs, const float* __restrict__ wf,
                                     const float* __restrict__ bf, const float* __restrict__ wm,
                                     const float* __restrict__ bm, float* __restrict__ out,
                                     int n, int tile, float* patch) {
    int h0 = (tile >> 3) << 4, w0 = (tile & 7) << 4;
    int t = threadIdx.x;
    const float* magn = mag + ((long)n << 18);
    for (int idx = t; idx < 16*324; idx += 1024) {
        int c = idx / 324, r = idx - c*324;
        int ph = r / 18, pw = r - ph*18;
        int gh = h0 - 1 + ph, gw = w0 - 1 + pw;
        float v = 0.f;
        if (gh >= 19 && gh < 109 && gw >= 19 && gw < 109)
            v = magn[(c<<14) + (gh<<7) + gw];
        patch[c*324 + r] = v;
    }
    __syncthreads();
    int oq = t >> 8, pix = t & 255;
    int ty = pix >> 4, tx = pix & 15;
    int h = h0 + ty, w = w0 + tx;
    bool in1 = (h >= 19 && h < 109 && w >= 19 && w < 109);
    unsigned long long bal = __ballot(in1);
    float res[4];
    if (bal != 0ull) {
        float acc[4];
#pragma unroll
        for (int j = 0; j < 4; ++j) acc[j] = bs[oq*4 + j];
        for (int c = 0; c < 16; ++c) {
            const float* pc = patch + c*324 + ty*18 + tx;
            const float* wc = ws3 + c*9;
#pragma unroll
            for (int dh = 0; dh < 3; ++dh) {
#pragma unroll
                for (int dw = 0; dw < 3; ++dw) {
                    float tap = pc[dh*18 + dw];
#pragma unroll
                    for (int j = 0; j < 4; ++j)
                        acc[j] = fmaf(wc[(oq*4 + j)*144 + dh*3 + dw], tap, acc[j]);
                }
            }
        }
#pragma unroll
        for (int j = 0; j < 4; ++j) res[j] = acc[j];
    }
    if (bal != ~0ull) {
        float acc2[4];
#pragma unroll
        for (int j = 0; j < 4; ++j) acc2[j] = bf[oq*4 + j];
#pragma unroll
        for (int half = 0; half < 2; ++half) {
            float xv[8];
#pragma unroll
            for (int c = 0; c < 8; ++c)
                xv[c] = magn[((half*8 + c)<<14) + (h<<7) + w];
#pragma unroll
            for (int c = 0; c < 8; ++c)
#pragma unroll
                for (int j = 0; j < 4; ++j)
                    acc2[j] = fmaf(wf[(oq*4 + j)*16 + half*8 + c], xv[c], acc2[j]);
        }
        if (!in1) {
#pragma unroll
            for (int j = 0; j < 4; ++j) res[j] = acc2[j];
        }
    }
    __syncthreads();               // all reads of patch complete
    float* resl = patch;           // reuse as [16][256]
#pragma unroll
    for (int j = 0; j < 4; ++j) resl[(oq*4 + j)*256 + pix] = res[j];
    __syncthreads();
    float rr[16];
#pragma unroll
    for (int o = 0; o < 16; ++o) rr[o] = resl[o*256 + pix];
#pragma unroll
    for (int j = 0; j < 4; ++j) {
        int o2 = oq*4 + j;
        float a = bm[o2];
#pragma unroll
        for (int o = 0; o < 16; ++o)
            a = fmaf(wm[o2*16 + o], rr[o], a);
        out[((long)((n<<4) + o2) << 14) + (h << 7) + w] = a;
    }
}

__global__ __launch_bounds__(1024, 8)
void k_point(const float* __restrict__ mag, const float* __restrict__ ws3,
             const float* __restrict__ bs, const float* __restrict__ wf,
             const float* __restrict__ bf, const float* __restrict__ wm,
             const float* __restrict__ bm, float* __restrict__ t2,
             const float* __restrict__ pha, const float* __restrict__ pw,
             const float* __restrict__ pb, float* __restrict__ t1,
             const float* __restrict__ x1, const float* __restrict__ c0w,
             const float* __restrict__ c0b, float* __restrict__ cat,
             const float* __restrict__ m65, const float* __restrict__ p65,
             const float* __restrict__ c1w, const float* __restrict__ c1b,
             float* __restrict__ t3, float* __restrict__ t4) {
    __shared__ float patch[16*324];
    int b = blockIdx.x;
    if (b < 256) {
        maskconv_body(mag, ws3, bs, wf, bf, wm, bm, t2, b >> 6, b & 63, patch);
    } else if (b < 384) {
        int i = b - 256;               // pha channel-mix (S=16384): 32 blocks/n
        mix16b(pha, pw, pb, t1, 16, 16384, i >> 5, (i & 31) << 9, 16384);
    } else if (b < 512) {
        int i = b - 384;               // conv_0: x1 ch0..15 -> cat ch0..15 (Ct=48)
        mix16b(x1, c0w, c0b, cat, 48, 16384, i >> 5, (i & 31) << 9, 16384);
    } else if (b < 580) {
        int i = b - 512;               // m65 mix (S=8320): 17 blocks/n
        mix16b(m65, c1w, c1b, t3, 16, 8320, i / 17, (i % 17) << 9, 8320);
    } else {
        int i = b - 580;               // p65 mix
        mix16b(p65, c1w, c1b, t4, 16, 8320, i / 17, (i % 17) << 9, 8320);
    }
}

// ---------------- launch ----------------------------------------------------
extern "C" void kernel_launch(void* const* d_in, const int* in_sizes, int n_in,
                              void* d_out, int out_size, void* d_ws, size_t ws_size,
                              hipStream_t stream) {
    (void)in_sizes; (void)n_in; (void)out_size; (void)d_ws; (void)ws_size;
    const float* x        = (const float*)d_in[0];
    const float* conv1_w  = (const float*)d_in[1];
    const float* mag_s_w  = (const float*)d_in[2];
    const float* mag_s_b  = (const float*)d_in[3];
    const float* mag_f_w  = (const float*)d_in[4];
    const float* mag_f_b  = (const float*)d_in[5];
    const float* mag_w_   = (const float*)d_in[6];
    const float* mag_b_   = (const float*)d_in[7];
    const float* pha_w_   = (const float*)d_in[8];
    const float* pha_b_   = (const float*)d_in[9];
    const float* conv_0_w = (const float*)d_in[10];
    const float* conv_0_b = (const float*)d_in[11];
    const float* conv_1_w = (const float*)d_in[12];
    const float* conv_1_b = (const float*)d_in[13];
    const float* conv2_w  = (const float*)d_in[14];
    float* outp = (float*)d_out;

    float2 *Mf, *MfT, *Mb, *MbT, *Fm, *IFm, *bufA, *bufB;
    float *x1, *mag, *pha, *m65, *p65, *t1, *t2, *t3, *t4, *cat;
    hipGetSymbolAddress((void**)&Mf,   HIP_SYMBOL(g_Mf));
    hipGetSymbolAddress((void**)&MfT,  HIP_SYMBOL(g_MfT));
    hipGetSymbolAddress((void**)&Mb,   HIP_SYMBOL(g_Mb));
    hipGetSymbolAddress((void**)&MbT,  HIP_SYMBOL(g_MbT));
    hipGetSymbolAddress((void**)&Fm,   HIP_SYMBOL(g_F));
    hipGetSymbolAddress((void**)&IFm,  HIP_SYMBOL(g_IF));
    hipGetSymbolAddress((void**)&bufA, HIP_SYMBOL(g_bufA));
    hipGetSymbolAddress((void**)&bufB, HIP_SYMBOL(g_bufB));
    hipGetSymbolAddress((void**)&x1,   HIP_SYMBOL(g_x1));
    hipGetSymbolAddress((void**)&mag,  HIP_SYMBOL(g_mag));
    hipGetSymbolAddress((void**)&pha,  HIP_SYMBOL(g_pha));
    hipGetSymbolAddress((void**)&m65,  HIP_SYMBOL(g_m65));
    hipGetSymbolAddress((void**)&p65,  HIP_SYMBOL(g_p65));
    hipGetSymbolAddress((void**)&t1,   HIP_SYMBOL(g_t1));
    hipGetSymbolAddress((void**)&t2,   HIP_SYMBOL(g_t2));
    hipGetSymbolAddress((void**)&t3,   HIP_SYMBOL(g_t3));
    hipGetSymbolAddress((void**)&t4,   HIP_SYMBOL(g_t4));
    hipGetSymbolAddress((void**)&cat,  HIP_SYMBOL(g_cat));

    dim3 bt(256, 1, 1);

    // stage 1: conv1 (x -> x1) + build Mf/MfT/F/IF
    k_conv1_build<<<dim3(128,4,2), bt, 0, stream>>>(x, conv1_w, x1);

    // stage 2: dual rmul (FRFT fwd -> bufA; FFT fwd -> bufB) + build Mb
    k_rmul_dual<1,1><<<dim3(136,8), bt, 0, stream>>>(
        MfT, x1, nullptr, nullptr, bufA, 16,
        Fm,  x1, nullptr, nullptr, bufB, 32);

    // stage 3: dual lmul (mag/pha full <- bufA; packed65 <- bufB)
    k_lmul_dual<1,4><<<dim3(128,8), bt, 0, stream>>>(
        Mf, bufA, mag, pha, 0,
        Fm, bufB, m65, p65, 0);

    // stage 4: maskconv(+mag mix) | pha mix | conv_0 | m65 mix | p65 mix
    k_point<<<648, dim3(1024,1,1), 0, stream>>>(mag, mag_s_w, mag_s_b, mag_f_w, mag_f_b,
                                                mag_w_, mag_b_, t2,
                                                pha, pha_w_, pha_b_, t1,
                                                x1, conv_0_w, conv_0_b, cat,
                                                m65, p65, conv_1_w, conv_1_b, t3, t4);

    // stage 5: dual rmul (FRFT bwd combine(t2,t1) -> bufA; irfft combine65(t3,t4) -> bufB)
    k_rmul_dual<2,3><<<dim3(128,8), bt, 0, stream>>>(
        MbT, nullptr, t2, t1, bufA, 0,
        IFm, nullptr, t3, t4, bufB, 0);

    // stage 6: dual lmul (abs -> cat ch16..31; real -> cat ch32..47)
    k_lmul_dual<2,3><<<dim3(128,8), bt, 0, stream>>>(
        Mb,  bufA, cat, nullptr, 16,
        IFm, bufB, cat, nullptr, 32);

    // stage 7: conv2 (cat -> out)
    k_conv2<<<dim3(128,4,2), bt, 0, stream>>>(cat, conv2_w, outp);
}

// Round 13
// 304.775 us; speedup vs baseline: 1.0953x; 1.0288x over previous
//
#include <hip/hip_runtime.h>
#include <math.h>

#define PI_D 3.14159265358979323846
#define TWO_PI_F 6.2831853071795864f

// ---------------- persistent device buffers ---------------------------------
__device__ __align__(16) float2 g_Mf [128*128];
__device__ __align__(16) float2 g_MfT[128*128];
__device__ __align__(16) float2 g_Mb [128*128];
__device__ __align__(16) float2 g_MbT[128*128];
__device__ __align__(16) float2 g_F  [128*128];   // symmetric
__device__ __align__(16) float2 g_IF [128*128];   // symmetric
__device__ __align__(16) float  g_x1 [4*48*16384];
__device__ __align__(16) float2 g_bufA[64*16384];
__device__ __align__(16) float2 g_bufB[64*16384];
__device__ __align__(16) float  g_mag[64*16384];
__device__ __align__(16) float  g_pha[64*16384];
__device__ __align__(16) float  g_m65[64*8320];
__device__ __align__(16) float  g_p65[64*8320];
__device__ __align__(16) float  g_t1 [64*16384];
__device__ __align__(16) float  g_t2 [64*16384];
__device__ __align__(16) float  g_t3 [64*8320];
__device__ __align__(16) float  g_t4 [64*8320];
__device__ __align__(16) float  g_cat[4*48*16384];

// ---------------- builder body -----------------------------------------------
__device__ inline void build_A_body(int tid) {
    if (tid >= 128*128) return;
    int o = tid >> 7, m = tid & 127;
    const double chc = -PI_D/128.0 * tan(PI_D/8.0) * 0.25;
    const double c   =  PI_D/(512.0*sin(PI_D/4.0));
    const double inv2pi = 1.0/(2.0*PI_D);
    float sr, si;
    {   // q = 2m term (sinc = 1)
        int n1 = 2*m - 127, tt = 2*(o - m);
        double ang = chc*(double)(n1*n1) + c*(double)(tt*tt);
        double r = ang*inv2pi; r -= floor(r);
        float af = (float)(r*2.0*PI_D);
        float sn, cs; __sincosf(af, &sn, &cs);
        sr = cs; si = sn;
    }
    for (int j = 0; j < 127; ++j) {
        int q  = 2*j + 1;
        int n1 = q - 127, tt = 2*o - q, d = q - 2*m;
        double ang = chc*(double)(n1*n1) + c*(double)(tt*tt);
        double r = ang*inv2pi; r -= floor(r);
        float af = (float)(r*2.0*PI_D);
        float s = (((d-1)>>1) & 1) ? -2.0f : 2.0f;
        s /= (3.14159265358979f*(float)d);
        float sn, cs; __sincosf(af, &sn, &cs);
        sr += s*cs; si += s*sn;
    }
    int n2 = 2*o - 127;
    double ph = chc*(double)(n2*n2) - PI_D/8.0;
    double r = ph*inv2pi; r -= floor(r);
    float pf = (float)(r*2.0*PI_D);
    float scale = (float)sqrt(c/PI_D);
    float sn, cs; __sincosf(pf, &sn, &cs);
    float cr = cs*scale, ci = sn*scale;
    float2 v = make_float2(sr*cr - si*ci, sr*ci + si*cr);
    g_Mf[tid] = v;
    g_MfT[(m<<7) + o] = v;
    int p = (o*m) & 127;
    float ang2 = TWO_PI_F*(float)p/128.0f;
    float sn2, cs2; __sincosf(ang2, &sn2, &cs2);
    g_F[tid]  = make_float2(cs2, -sn2);
    g_IF[tid] = make_float2(cs2*0.0078125f, sn2*0.0078125f);
}

// ---------------- stream loaders (rmul T-side, LM2/3 staging) ----------------
template<int LM>
__device__ inline void load_T4(float2* tr, const float* mp, const float* pp,
                               const float* Trl, int hh, int w4) {
    if (LM == 2) {
#pragma unroll
        for (int i = 0; i < 4; ++i) {
            int idx = (hh<<7) + w4 + i;
            float m = mp[idx], ph = pp[idx];
            float sn, cs; __sincosf(ph, &sn, &cs);
            tr[i] = make_float2(m*cs, m*sn);
        }
    } else {
#pragma unroll
        for (int i = 0; i < 4; ++i) {
            int w = w4 + i;
            int h2 = hh, w2 = w; float sg = 1.f;
            if (w >= 65) { h2 = (128 - hh) & 127; w2 = 128 - w; sg = -1.f; }
            int idx = h2*65 + w2;
            float m = mp[idx], ph = pp[idx];
            float sn, cs; __sincosf(ph, &sn, &cs);
            tr[i] = make_float2(m*cs, sg*m*sn);
        }
    }
}

__device__ inline void cfma(float2& a, float sx, float sy, float mx, float my) {
    a.x = fmaf(sx, mx, a.x); a.x = fmaf(-sy, my, a.x);
    a.y = fmaf(sx, my, a.y); a.y = fmaf(sy, mx, a.y);
}

// ---------------- rmul body (round-5 proven form) ----------------------------
// LM1: stream rows via wave-uniform global reads, m-side direct global, zero
// barriers. LM2/3: stream via sincos into Ssh once (one barrier), then read.
template<int LM>
__device__ inline void rmul_body(const float2* __restrict__ MT, const float* __restrict__ Trl,
                                 const float* __restrict__ mp_, const float* __restrict__ pp_,
                                 float2* __restrict__ out, int cstart,
                                 int p, int r0, int t, float2* Ssh) {
    constexpr bool RS = (LM == 1);
    const float* Trp = nullptr; const float* mp = nullptr; const float* pp = nullptr;
    if (LM == 1) { int n = p >> 4, c = p & 15; Trp = Trl + ((long)(n*48 + cstart + c) << 14); }
    if (LM == 2) { mp = mp_ + ((long)p << 14); pp = pp_ + ((long)p << 14); }
    if (LM == 3) { mp = mp_ + (long)p*8320;   pp = pp_ + (long)p*8320; }
    int cq = t & 63, rp = t >> 6;
    const float* Tr_row[4];
    if (RS) {
#pragma unroll
        for (int i = 0; i < 4; ++i) {
            int ro = __builtin_amdgcn_readfirstlane((r0 + (rp<<2) + i) << 7);
            Tr_row[i] = Trp + ro;
        }
    } else {
        for (int u = t; u < 512; u += 256) {
            int row = u >> 5, w4 = (u & 31) << 2;
            float2 tr4[4];
            load_T4<LM>(tr4, mp, pp, Trp, r0 + row, w4);
            float4* d = (float4*)&Ssh[(row << 7) + w4];
            d[0] = make_float4(tr4[0].x, tr4[0].y, tr4[1].x, tr4[1].y);
            d[1] = make_float4(tr4[2].x, tr4[2].y, tr4[3].x, tr4[3].y);
        }
        __syncthreads();
    }
    float2 acc[4][2] = {};
#pragma unroll 8
    for (int k2 = 0; k2 < 64; ++k2) {
        int k = k2 << 1;
        float4 m0 = *(const float4*)&MT[(k << 7) + (cq<<1)];
        float4 m1 = *(const float4*)&MT[((k+1) << 7) + (cq<<1)];
        if (RS) {
            float2 sr4[4];
#pragma unroll
            for (int i = 0; i < 4; ++i)
                sr4[i] = *(const float2*)(Tr_row[i] + k);
#pragma unroll
            for (int i = 0; i < 4; ++i) {
                acc[i][0].x = fmaf(sr4[i].x, m0.x, acc[i][0].x);
                acc[i][0].y = fmaf(sr4[i].x, m0.y, acc[i][0].y);
                acc[i][1].x = fmaf(sr4[i].x, m0.z, acc[i][1].x);
                acc[i][1].y = fmaf(sr4[i].x, m0.w, acc[i][1].y);
                acc[i][0].x = fmaf(sr4[i].y, m1.x, acc[i][0].x);
                acc[i][0].y = fmaf(sr4[i].y, m1.y, acc[i][0].y);
                acc[i][1].x = fmaf(sr4[i].y, m1.z, acc[i][1].x);
                acc[i][1].y = fmaf(sr4[i].y, m1.w, acc[i][1].y);
            }
        } else {
            float4 s2[4];
#pragma unroll
            for (int i = 0; i < 4; ++i)
                s2[i] = *(const float4*)&Ssh[(((rp<<2)+i) << 7) + k];
#pragma unroll
            for (int i = 0; i < 4; ++i) {
                cfma(acc[i][0], s2[i].x, s2[i].y, m0.x, m0.y);
                cfma(acc[i][1], s2[i].x, s2[i].y, m0.z, m0.w);
                cfma(acc[i][0], s2[i].z, s2[i].w, m1.x, m1.y);
                cfma(acc[i][1], s2[i].z, s2[i].w, m1.z, m1.w);
            }
        }
    }
    long base = ((long)p << 14);
#pragma unroll
    for (int i = 0; i < 4; ++i) {
        float4* dst = (float4*)(out + base + ((long)(r0 + (rp<<2) + i) << 7) + (cq<<1));
        *dst = make_float4(acc[i][0].x, acc[i][0].y, acc[i][1].x, acc[i][1].y);
    }
}

// ---------------- lmul body (round-5 proven form) ----------------------------
// A-side rows: wave-uniform global reads. T-side: direct global coalesced row
// reads. Zero LDS, zero barriers. EPI 1: mag/pha  2: abs->cat  3: real->cat
// 4: packed65
template<int EPI>
__device__ inline void lmul_body(const float2* __restrict__ A, const float2* __restrict__ in,
                                 float* __restrict__ o1, float* __restrict__ o2, int coff,
                                 int p, int j0, int t) {
    const float2* T = in + ((long)p << 14);
    int cq = t & 63, rp = t >> 6;
    const float2* Arow[4];
#pragma unroll
    for (int i = 0; i < 4; ++i) {
        int ro = __builtin_amdgcn_readfirstlane((j0 + (rp<<2) + i) << 7);
        Arow[i] = A + ro;
    }
    float2 acc[4][2] = {};
#pragma unroll 8
    for (int k2 = 0; k2 < 64; ++k2) {
        int k = k2 << 1;
        float4 m0 = *(const float4*)&T[(k << 7) + (cq<<1)];
        float4 m1 = *(const float4*)&T[((k+1) << 7) + (cq<<1)];
        float4 s2[4];
#pragma unroll
        for (int i = 0; i < 4; ++i)
            s2[i] = *(const float4*)(Arow[i] + k);
#pragma unroll
        for (int i = 0; i < 4; ++i) {
            if (EPI == 3) {
                acc[i][0].x = fmaf(s2[i].x, m0.x, acc[i][0].x);
                acc[i][0].x = fmaf(-s2[i].y, m0.y, acc[i][0].x);
                acc[i][1].x = fmaf(s2[i].x, m0.z, acc[i][1].x);
                acc[i][1].x = fmaf(-s2[i].y, m0.w, acc[i][1].x);
                acc[i][0].x = fmaf(s2[i].z, m1.x, acc[i][0].x);
                acc[i][0].x = fmaf(-s2[i].w, m1.y, acc[i][0].x);
                acc[i][1].x = fmaf(s2[i].z, m1.z, acc[i][1].x);
                acc[i][1].x = fmaf(-s2[i].w, m1.w, acc[i][1].x);
            } else {
                cfma(acc[i][0], s2[i].x, s2[i].y, m0.x, m0.y);
                cfma(acc[i][1], s2[i].x, s2[i].y, m0.z, m0.w);
                cfma(acc[i][0], s2[i].z, s2[i].w, m1.x, m1.y);
                cfma(acc[i][1], s2[i].z, s2[i].w, m1.z, m1.w);
            }
        }
    }
#pragma unroll
    for (int i = 0; i < 4; ++i) {
        int jj = j0 + (rp<<2) + i;
        int ww0 = cq << 1;
        float2 v0 = acc[i][0], v1 = acc[i][1];
        if (EPI == 1) {
            long idx = ((long)p << 14) + ((long)jj << 7) + ww0;
            *(float2*)&o1[idx] = make_float2(sqrtf(v0.x*v0.x + v0.y*v0.y),
                                             sqrtf(v1.x*v1.x + v1.y*v1.y));
            *(float2*)&o2[idx] = make_float2(atan2f(v0.y, v0.x), atan2f(v1.y, v1.x));
        } else if (EPI == 2) {
            int n = p >> 4, c = p & 15;
            long idx = ((long)(n*48 + coff + c) << 14) + ((long)jj << 7) + ww0;
            *(float2*)&o1[idx] = make_float2(sqrtf(v0.x*v0.x + v0.y*v0.y),
                                             sqrtf(v1.x*v1.x + v1.y*v1.y));
        } else if (EPI == 3) {
            int n = p >> 4, c = p & 15;
            long idx = ((long)(n*48 + coff + c) << 14) + ((long)jj << 7) + ww0;
            *(float2*)&o1[idx] = make_float2(v0.x, v1.x);
        } else if (EPI == 4) {
            if (ww0 < 65) {
                long idx = (long)p*8320 + jj*65 + ww0;
                o1[idx] = sqrtf(v0.x*v0.x + v0.y*v0.y);
                o2[idx] = atan2f(v0.y, v0.x);
                if (ww0 + 1 < 65) {
                    o1[idx+1] = sqrtf(v1.x*v1.x + v1.y*v1.y);
                    o2[idx+1] = atan2f(v1.y, v1.x);
                }
            }
        }
    }
}

// ---------------- dual rmul kernel (+ Mb build at bx>=128) -------------------
// grid (136, 8): bx<128 -> plane (A: 0..63, B: 64..127), by = strip.
// id % 8 == bx % 8 -> all strips of a plane land on one XCD.
template<int LMA, int LMB>
__global__ __launch_bounds__(256, 4)
void k_rmul_dual(const float2* __restrict__ MTa, const float* __restrict__ TrlA,
                 const float* __restrict__ mpA, const float* __restrict__ ppA,
                 float2* __restrict__ outA, int cstartA,
                 const float2* __restrict__ MTb, const float* __restrict__ TrlB,
                 const float* __restrict__ mpB, const float* __restrict__ ppB,
                 float2* __restrict__ outB, int cstartB) {
    __shared__ __align__(16) float2 Ssh[(LMA == 1 && LMB == 1) ? 2 : 16*128];
    __shared__ float2 W[128];
    int bx = blockIdx.x, by = blockIdx.y, t = threadIdx.x;
    if (bx >= 128) {
        int b = (bx - 128)*8 + by;
        if (b < 64) {
            if (t < 128) {
                float ang = TWO_PI_F*(float)t/128.0f;
                float sn, cs; __sincosf(ang, &sn, &cs);
                float invs = 0.08838834764831845f;
                W[t] = make_float2(cs*invs, sn*invs);
            }
            __syncthreads();
            int tid = b*256 + t;
            int o = tid >> 7, m = tid & 127;
            float sr = 0.f, si = 0.f;
            for (int r = 0; r < 128; ++r) {
                float2 a = g_Mf[(o<<7) + r];
                int k = ((r+64)*(m+64)) & 127;
                float2 w = W[k];
                sr += a.x*w.x - a.y*w.y;
                si += a.x*w.y + a.y*w.x;
            }
            float2 v = make_float2(sr, si);
            g_Mb[tid] = v;
            g_MbT[(m<<7) + o] = v;
        }
        return;
    }
    int p = bx & 63, r0 = by << 4;
    if (bx < 64) rmul_body<LMA>(MTa, TrlA, mpA, ppA, outA, cstartA, p, r0, t, Ssh);
    else         rmul_body<LMB>(MTb, TrlB, mpB, ppB, outB, cstartB, p, r0, t, Ssh);
}

// ---------------- dual lmul kernel (XCD-pinned planes, no LDS) ---------------
template<int EPIA, int EPIB>
__global__ __launch_bounds__(256, 4)
void k_lmul_dual(const float2* __restrict__ Aa, const float2* __restrict__ inA,
                 float* __restrict__ o1A, float* __restrict__ o2A, int coffA,
                 const float2* __restrict__ Ab, const float2* __restrict__ inB,
                 float* __restrict__ o1B, float* __restrict__ o2B, int coffB) {
    int bx = blockIdx.x, j0 = blockIdx.y << 4, t = threadIdx.x;
    int p = bx & 63;
    if (bx < 64) lmul_body<EPIA>(Aa, inA, o1A, o2A, coffA, p, j0, t);
    else         lmul_body<EPIB>(Ab, inB, o1B, o2B, coffB, p, j0, t);
}

// ---------------- wave-level 1x1 conv body (KSPLIT=1, no LDS) -----------------
template<int CIN, int COUT, int OSPLIT>
__device__ inline void wconv_body(const float* __restrict__ in, const float* __restrict__ wgt,
                                  const float* __restrict__ bias, float* __restrict__ out,
                                  int S, int Ctin, int cstart, int Ctout, int costart,
                                  int n, int sblk) {
    constexpr int OW = COUT / OSPLIT;
    int t = threadIdx.x, lane = t & 63;
    int oq = __builtin_amdgcn_readfirstlane(t >> 6);
    int s0 = sblk << 7;
    const float* inb = in + ((long)(n*Ctin + cstart))*S + s0 + (lane<<1);
    const float* wb  = wgt + (oq*OW)*CIN;
    float2 acc[OW];
#pragma unroll
    for (int j = 0; j < OW; ++j) acc[j] = make_float2(0.f, 0.f);
#pragma unroll 4
    for (int c = 0; c < CIN; ++c) {
        float2 xv = *(const float2*)(inb + (long)c*S);
#pragma unroll
        for (int j = 0; j < OW; ++j) {
            float w = wb[j*CIN + c];
            acc[j].x = fmaf(w, xv.x, acc[j].x);
            acc[j].y = fmaf(w, xv.y, acc[j].y);
        }
    }
#pragma unroll
    for (int j = 0; j < OW; ++j) {
        int o = oq*OW + j;
        float b = bias ? bias[o] : 0.f;
        *(float2*)(out + ((long)(n*Ctout + costart + o))*S + s0 + (lane<<1))
            = make_float2(acc[j].x + b, acc[j].y + b);
    }
}

// ---------------- stage 1: conv1 + matrix builder ----------------------------
// grid (128,4,3): z<2 -> compute 24-output half (4 waves x 6 outputs), 1024
// compute blocks = 4 blocks/CU = 16 waves/CU; z==2 -> builder.
__global__ __launch_bounds__(256, 4)
void k_conv1_build(const float* __restrict__ x, const float* __restrict__ w,
                   float* __restrict__ x1) {
    int z = blockIdx.z;
    if (z < 2) {
        wconv_body<192,24,4>(x, w + z*24*192, nullptr, x1, 16384, 192, 0, 48, z*24,
                             blockIdx.y, blockIdx.x);
    } else {
        int b = blockIdx.y*gridDim.x + blockIdx.x;
        if (b < 64) build_A_body(b*256 + threadIdx.x);
    }
}

// ---------------- stage 7: conv2 ---------------------------------------------
// grid (128,4,2): z selects 96-output half; 4 waves x 24 outputs each,
// KSPLIT=1, zero LDS, LB(256,4) -> 1024 blocks = 4 blocks/CU.
__global__ __launch_bounds__(256, 4)
void k_conv2(const float* __restrict__ in, const float* __restrict__ wgt,
             float* __restrict__ out) {
    int z = blockIdx.z;
    wconv_body<48,96,4>(in, wgt + z*96*48, nullptr, out, 16384, 48, 0, 192, z*96,
                        blockIdx.y, blockIdx.x);
}

// ---------------- pointwise stage: maskconv + 4 channel-mixes ----------------
__device__ inline void mix16b(const float* __restrict__ in, const float* __restrict__ w,
                              const float* __restrict__ b, float* __restrict__ out,
                              int Ctin, int S, int n, int s0base, int Slim) {
    int t = threadIdx.x, lane = t & 63;
    int wv = __builtin_amdgcn_readfirstlane(t >> 6);
    int oq = wv & 3, pg = wv >> 2;
    int s0 = s0base + (pg << 7);
    if (s0 >= Slim) return;                    // no __syncthreads in this path
    const float* inb = in + ((long)(n*Ctin))*S + s0 + (lane<<1);
    float2 acc[4];
#pragma unroll
    for (int j = 0; j < 4; ++j) {
        float bb = b ? b[oq*4 + j] : 0.f;
        acc[j] = make_float2(bb, bb);
    }
#pragma unroll
    for (int half = 0; half < 2; ++half) {
        float2 xv[8];
#pragma unroll
        for (int c = 0; c < 8; ++c)
            xv[c] = *(const float2*)(inb + (long)(half*8 + c)*S);
#pragma unroll
        for (int c = 0; c < 8; ++c) {
#pragma unroll
            for (int j = 0; j < 4; ++j) {
                float ww = w[(oq*4 + j)*16 + half*8 + c];
                acc[j].x = fmaf(ww, xv[c].x, acc[j].x);
                acc[j].y = fmaf(ww, xv[c].y, acc[j].y);
            }
        }
    }
#pragma unroll
    for (int j = 0; j < 4; ++j) {
        int o = oq*4 + j;
        *(float2*)(out + ((long)(n*Ctin + o))*S + s0 + (lane<<1)) = acc[j];
    }
}

__device__ inline void maskconv_body(const float* __restrict__ mag, const float* __restrict__ ws3,
                                     const float* __restrict__ bs, const float* __restrict__ wf,
                                     const float* __restrict__ bf, const float* __restrict__ wm,
                                     const float* __restrict__ bm, float* __restrict__ out,
                                     int n, int tile, float* patch) {
    int h0 = (tile >> 3) << 4, w0 = (tile & 7) << 4;
    int t = threadIdx.x;
    const float* magn = mag + ((long)n << 18);
    for (int idx = t; idx < 16*324; idx += 1024) {
        int c = idx / 324, r = idx - c*324;
        int ph = r / 18, pw = r - ph*18;
        int gh = h0 - 1 + ph, gw = w0 - 1 + pw;
        float v = 0.f;
        if (gh >= 19 && gh < 109 && gw >= 19 && gw < 109)
            v = magn[(c<<14) + (gh<<7) + gw];
        patch[c*324 + r] = v;
    }
    __syncthreads();
    int oq = t >> 8, pix = t & 255;
    int ty = pix >> 4, tx = pix & 15;
    int h = h0 + ty, w = w0 + tx;
    bool in1 = (h >= 19 && h < 109 && w >= 19 && w < 109);
    unsigned long long bal = __ballot(in1);
    float res[4];
    if (bal != 0ull) {
        float acc[4];
#pragma unroll
        for (int j = 0; j < 4; ++j) acc[j] = bs[oq*4 + j];
        for (int c = 0; c < 16; ++c) {
            const float* pc = patch + c*324 + ty*18 + tx;
            const float* wc = ws3 + c*9;
#pragma unroll
            for (int dh = 0; dh < 3; ++dh) {
#pragma unroll
                for (int dw = 0; dw < 3; ++dw) {
                    float tap = pc[dh*18 + dw];
#pragma unroll
                    for (int j = 0; j < 4; ++j)
                        acc[j] = fmaf(wc[(oq*4 + j)*144 + dh*3 + dw], tap, acc[j]);
                }
            }
        }
#pragma unroll
        for (int j = 0; j < 4; ++j) res[j] = acc[j];
    }
    if (bal != ~0ull) {
        float acc2[4];
#pragma unroll
        for (int j = 0; j < 4; ++j) acc2[j] = bf[oq*4 + j];
#pragma unroll
        for (int half = 0; half < 2; ++half) {
            float xv[8];
#pragma unroll
            for (int c = 0; c < 8; ++c)
                xv[c] = magn[((half*8 + c)<<14) + (h<<7) + w];
#pragma unroll
            for (int c = 0; c < 8; ++c)
#pragma unroll
                for (int j = 0; j < 4; ++j)
                    acc2[j] = fmaf(wf[(oq*4 + j)*16 + half*8 + c], xv[c], acc2[j]);
        }
        if (!in1) {
#pragma unroll
            for (int j = 0; j < 4; ++j) res[j] = acc2[j];
        }
    }
    __syncthreads();               // all reads of patch complete
    float* resl = patch;           // reuse as [16][256]
#pragma unroll
    for (int j = 0; j < 4; ++j) resl[(oq*4 + j)*256 + pix] = res[j];
    __syncthreads();
    float rr[16];
#pragma unroll
    for (int o = 0; o < 16; ++o) rr[o] = resl[o*256 + pix];
#pragma unroll
    for (int j = 0; j < 4; ++j) {
        int o2 = oq*4 + j;
        float a = bm[o2];
#pragma unroll
        for (int o = 0; o < 16; ++o)
            a = fmaf(wm[o2*16 + o], rr[o], a);
        out[((long)((n<<4) + o2) << 14) + (h << 7) + w] = a;
    }
}

__global__ __launch_bounds__(1024, 8)
void k_point(const float* __restrict__ mag, const float* __restrict__ ws3,
             const float* __restrict__ bs, const float* __restrict__ wf,
             const float* __restrict__ bf, const float* __restrict__ wm,
             const float* __restrict__ bm, float* __restrict__ t2,
             const float* __restrict__ pha, const float* __restrict__ pw,
             const float* __restrict__ pb, float* __restrict__ t1,
             const float* __restrict__ x1, const float* __restrict__ c0w,
             const float* __restrict__ c0b, float* __restrict__ cat,
             const float* __restrict__ m65, const float* __restrict__ p65,
             const float* __restrict__ c1w, const float* __restrict__ c1b,
             float* __restrict__ t3, float* __restrict__ t4) {
    __shared__ float patch[16*324];
    int b = blockIdx.x;
    if (b < 256) {
        maskconv_body(mag, ws3, bs, wf, bf, wm, bm, t2, b >> 6, b & 63, patch);
    } else if (b < 384) {
        int i = b - 256;               // pha channel-mix (S=16384): 32 blocks/n
        mix16b(pha, pw, pb, t1, 16, 16384, i >> 5, (i & 31) << 9, 16384);
    } else if (b < 512) {
        int i = b - 384;               // conv_0: x1 ch0..15 -> cat ch0..15 (Ct=48)
        mix16b(x1, c0w, c0b, cat, 48, 16384, i >> 5, (i & 31) << 9, 16384);
    } else if (b < 580) {
        int i = b - 512;               // m65 mix (S=8320): 17 blocks/n
        mix16b(m65, c1w, c1b, t3, 16, 8320, i / 17, (i % 17) << 9, 8320);
    } else {
        int i = b - 580;               // p65 mix
        mix16b(p65, c1w, c1b, t4, 16, 8320, i / 17, (i % 17) << 9, 8320);
    }
}

// ---------------- launch ----------------------------------------------------
extern "C" void kernel_launch(void* const* d_in, const int* in_sizes, int n_in,
                              void* d_out, int out_size, void* d_ws, size_t ws_size,
                              hipStream_t stream) {
    (void)in_sizes; (void)n_in; (void)out_size; (void)d_ws; (void)ws_size;
    const float* x        = (const float*)d_in[0];
    const float* conv1_w  = (const float*)d_in[1];
    const float* mag_s_w  = (const float*)d_in[2];
    const float* mag_s_b  = (const float*)d_in[3];
    const float* mag_f_w  = (const float*)d_in[4];
    const float* mag_f_b  = (const float*)d_in[5];
    const float* mag_w_   = (const float*)d_in[6];
    const float* mag_b_   = (const float*)d_in[7];
    const float* pha_w_   = (const float*)d_in[8];
    const float* pha_b_   = (const float*)d_in[9];
    const float* conv_0_w = (const float*)d_in[10];
    const float* conv_0_b = (const float*)d_in[11];
    const float* conv_1_w = (const float*)d_in[12];
    const float* conv_1_b = (const float*)d_in[13];
    const float* conv2_w  = (const float*)d_in[14];
    float* outp = (float*)d_out;

    float2 *Mf, *MfT, *Mb, *MbT, *Fm, *IFm, *bufA, *bufB;
    float *x1, *mag, *pha, *m65, *p65, *t1, *t2, *t3, *t4, *cat;
    hipGetSymbolAddress((void**)&Mf,   HIP_SYMBOL(g_Mf));
    hipGetSymbolAddress((void**)&MfT,  HIP_SYMBOL(g_MfT));
    hipGetSymbolAddress((void**)&Mb,   HIP_SYMBOL(g_Mb));
    hipGetSymbolAddress((void**)&MbT,  HIP_SYMBOL(g_MbT));
    hipGetSymbolAddress((void**)&Fm,   HIP_SYMBOL(g_F));
    hipGetSymbolAddress((void**)&IFm,  HIP_SYMBOL(g_IF));
    hipGetSymbolAddress((void**)&bufA, HIP_SYMBOL(g_bufA));
    hipGetSymbolAddress((void**)&bufB, HIP_SYMBOL(g_bufB));
    hipGetSymbolAddress((void**)&x1,   HIP_SYMBOL(g_x1));
    hipGetSymbolAddress((void**)&mag,  HIP_SYMBOL(g_mag));
    hipGetSymbolAddress((void**)&pha,  HIP_SYMBOL(g_pha));
    hipGetSymbolAddress((void**)&m65,  HIP_SYMBOL(g_m65));
    hipGetSymbolAddress((void**)&p65,  HIP_SYMBOL(g_p65));
    hipGetSymbolAddress((void**)&t1,   HIP_SYMBOL(g_t1));
    hipGetSymbolAddress((void**)&t2,   HIP_SYMBOL(g_t2));
    hipGetSymbolAddress((void**)&t3,   HIP_SYMBOL(g_t3));
    hipGetSymbolAddress((void**)&t4,   HIP_SYMBOL(g_t4));
    hipGetSymbolAddress((void**)&cat,  HIP_SYMBOL(g_cat));

    dim3 bt(256, 1, 1);

    // stage 1: conv1 (x -> x1, z<2) + build Mf/MfT/F/IF (z==2)
    k_conv1_build<<<dim3(128,4,3), bt, 0, stream>>>(x, conv1_w, x1);

    // stage 2: dual rmul (FRFT fwd -> bufA; FFT fwd -> bufB) + build Mb
    k_rmul_dual<1,1><<<dim3(136,8), bt, 0, stream>>>(
        MfT, x1, nullptr, nullptr, bufA, 16,
        Fm,  x1, nullptr, nullptr, bufB, 32);

    // stage 3: dual lmul (mag/pha full <- bufA; packed65 <- bufB)
    k_lmul_dual<1,4><<<dim3(128,8), bt, 0, stream>>>(
        Mf, bufA, mag, pha, 0,
        Fm, bufB, m65, p65, 0);

    // stage 4: maskconv(+mag mix) | pha mix | conv_0 | m65 mix | p65 mix
    k_point<<<648, dim3(1024,1,1), 0, stream>>>(mag, mag_s_w, mag_s_b, mag_f_w, mag_f_b,
                                                mag_w_, mag_b_, t2,
                                                pha, pha_w_, pha_b_, t1,
                                                x1, conv_0_w, conv_0_b, cat,
                                                m65, p65, conv_1_w, conv_1_b, t3, t4);

    // stage 5: dual rmul (FRFT bwd combine(t2,t1) -> bufA; irfft combine65(t3,t4) -> bufB)
    k_rmul_dual<2,3><<<dim3(128,8), bt, 0, stream>>>(
        MbT, nullptr, t2, t1, bufA, 0,
        IFm, nullptr, t3, t4, bufB, 0);

    // stage 6: dual lmul (abs -> cat ch16..31; real -> cat ch32..47)
    k_lmul_dual<2,3><<<dim3(128,8), bt, 0, stream>>>(
        Mb,  bufA, cat, nullptr, 16,
        IFm, bufB, cat, nullptr, 32);

    // stage 7: conv2 (cat -> out)
    k_conv2<<<dim3(128,4,2), bt, 0, stream>>>(cat, conv2_w, outp);
}

// Round 14
// 293.635 us; speedup vs baseline: 1.1369x; 1.0379x over previous
//
#include <hip/hip_runtime.h>
#include <math.h>

#define PI_D 3.14159265358979323846
#define TWO_PI_F 6.2831853071795864f

// ---------------- persistent device buffers ---------------------------------
__device__ __align__(16) float2 g_Mf [128*128];
__device__ __align__(16) float2 g_MfT[128*128];
__device__ __align__(16) float2 g_Mb [128*128];
__device__ __align__(16) float2 g_MbT[128*128];
__device__ __align__(16) float2 g_F  [128*128];   // symmetric
__device__ __align__(16) float2 g_IF [128*128];   // symmetric
__device__ __align__(16) float  g_x1 [4*48*16384];
__device__ __align__(16) float2 g_bufA[64*16384];
__device__ __align__(16) float2 g_bufB[64*16384];
__device__ __align__(16) float  g_mag[64*16384];
__device__ __align__(16) float  g_pha[64*16384];
__device__ __align__(16) float  g_m65[64*8320];
__device__ __align__(16) float  g_p65[64*8320];
__device__ __align__(16) float  g_t1 [64*16384];
__device__ __align__(16) float  g_t2 [64*16384];
__device__ __align__(16) float  g_t3 [64*8320];
__device__ __align__(16) float  g_t4 [64*8320];
__device__ __align__(16) float  g_cat[4*48*16384];

// ---------------- builder body -----------------------------------------------
__device__ inline void build_A_body(int tid) {
    if (tid >= 128*128) return;
    int o = tid >> 7, m = tid & 127;
    const double chc = -PI_D/128.0 * tan(PI_D/8.0) * 0.25;
    const double c   =  PI_D/(512.0*sin(PI_D/4.0));
    const double inv2pi = 1.0/(2.0*PI_D);
    float sr, si;
    {   // q = 2m term (sinc = 1)
        int n1 = 2*m - 127, tt = 2*(o - m);
        double ang = chc*(double)(n1*n1) + c*(double)(tt*tt);
        double r = ang*inv2pi; r -= floor(r);
        float af = (float)(r*2.0*PI_D);
        float sn, cs; __sincosf(af, &sn, &cs);
        sr = cs; si = sn;
    }
    for (int j = 0; j < 127; ++j) {
        int q  = 2*j + 1;
        int n1 = q - 127, tt = 2*o - q, d = q - 2*m;
        double ang = chc*(double)(n1*n1) + c*(double)(tt*tt);
        double r = ang*inv2pi; r -= floor(r);
        float af = (float)(r*2.0*PI_D);
        float s = (((d-1)>>1) & 1) ? -2.0f : 2.0f;
        s /= (3.14159265358979f*(float)d);
        float sn, cs; __sincosf(af, &sn, &cs);
        sr += s*cs; si += s*sn;
    }
    int n2 = 2*o - 127;
    double ph = chc*(double)(n2*n2) - PI_D/8.0;
    double r = ph*inv2pi; r -= floor(r);
    float pf = (float)(r*2.0*PI_D);
    float scale = (float)sqrt(c/PI_D);
    float sn, cs; __sincosf(pf, &sn, &cs);
    float cr = cs*scale, ci = sn*scale;
    float2 v = make_float2(sr*cr - si*ci, sr*ci + si*cr);
    g_Mf[tid] = v;
    g_MfT[(m<<7) + o] = v;
    int p = (o*m) & 127;
    float ang2 = TWO_PI_F*(float)p/128.0f;
    float sn2, cs2; __sincosf(ang2, &sn2, &cs2);
    g_F[tid]  = make_float2(cs2, -sn2);
    g_IF[tid] = make_float2(cs2*0.0078125f, sn2*0.0078125f);
}

// ---------------- stream loaders (rmul T-side, LM2/3 staging) ----------------
template<int LM>
__device__ inline void load_T4(float2* tr, const float* mp, const float* pp,
                               const float* Trl, int hh, int w4) {
    if (LM == 2) {
#pragma unroll
        for (int i = 0; i < 4; ++i) {
            int idx = (hh<<7) + w4 + i;
            float m = mp[idx], ph = pp[idx];
            float sn, cs; __sincosf(ph, &sn, &cs);
            tr[i] = make_float2(m*cs, m*sn);
        }
    } else {
#pragma unroll
        for (int i = 0; i < 4; ++i) {
            int w = w4 + i;
            int h2 = hh, w2 = w; float sg = 1.f;
            if (w >= 65) { h2 = (128 - hh) & 127; w2 = 128 - w; sg = -1.f; }
            int idx = h2*65 + w2;
            float m = mp[idx], ph = pp[idx];
            float sn, cs; __sincosf(ph, &sn, &cs);
            tr[i] = make_float2(m*cs, sg*m*sn);
        }
    }
}

__device__ inline void cfma(float2& a, float sx, float sy, float mx, float my) {
    a.x = fmaf(sx, mx, a.x); a.x = fmaf(-sy, my, a.x);
    a.y = fmaf(sx, my, a.y); a.y = fmaf(sy, mx, a.y);
}

// ---------------- rmul body (round-5 proven form) ----------------------------
// LM1: stream rows via wave-uniform global reads, m-side direct global, zero
// barriers. LM2/3: stream via sincos into Ssh once (one barrier), then read.
template<int LM>
__device__ inline void rmul_body(const float2* __restrict__ MT, const float* __restrict__ Trl,
                                 const float* __restrict__ mp_, const float* __restrict__ pp_,
                                 float2* __restrict__ out, int cstart,
                                 int p, int r0, int t, float2* Ssh) {
    constexpr bool RS = (LM == 1);
    const float* Trp = nullptr; const float* mp = nullptr; const float* pp = nullptr;
    if (LM == 1) { int n = p >> 4, c = p & 15; Trp = Trl + ((long)(n*48 + cstart + c) << 14); }
    if (LM == 2) { mp = mp_ + ((long)p << 14); pp = pp_ + ((long)p << 14); }
    if (LM == 3) { mp = mp_ + (long)p*8320;   pp = pp_ + (long)p*8320; }
    int cq = t & 63, rp = t >> 6;
    const float* Tr_row[4];
    if (RS) {
#pragma unroll
        for (int i = 0; i < 4; ++i) {
            int ro = __builtin_amdgcn_readfirstlane((r0 + (rp<<2) + i) << 7);
            Tr_row[i] = Trp + ro;
        }
    } else {
        for (int u = t; u < 512; u += 256) {
            int row = u >> 5, w4 = (u & 31) << 2;
            float2 tr4[4];
            load_T4<LM>(tr4, mp, pp, Trp, r0 + row, w4);
            float4* d = (float4*)&Ssh[(row << 7) + w4];
            d[0] = make_float4(tr4[0].x, tr4[0].y, tr4[1].x, tr4[1].y);
            d[1] = make_float4(tr4[2].x, tr4[2].y, tr4[3].x, tr4[3].y);
        }
        __syncthreads();
    }
    float2 acc[4][2] = {};
#pragma unroll 8
    for (int k2 = 0; k2 < 64; ++k2) {
        int k = k2 << 1;
        float4 m0 = *(const float4*)&MT[(k << 7) + (cq<<1)];
        float4 m1 = *(const float4*)&MT[((k+1) << 7) + (cq<<1)];
        if (RS) {
            float2 sr4[4];
#pragma unroll
            for (int i = 0; i < 4; ++i)
                sr4[i] = *(const float2*)(Tr_row[i] + k);
#pragma unroll
            for (int i = 0; i < 4; ++i) {
                acc[i][0].x = fmaf(sr4[i].x, m0.x, acc[i][0].x);
                acc[i][0].y = fmaf(sr4[i].x, m0.y, acc[i][0].y);
                acc[i][1].x = fmaf(sr4[i].x, m0.z, acc[i][1].x);
                acc[i][1].y = fmaf(sr4[i].x, m0.w, acc[i][1].y);
                acc[i][0].x = fmaf(sr4[i].y, m1.x, acc[i][0].x);
                acc[i][0].y = fmaf(sr4[i].y, m1.y, acc[i][0].y);
                acc[i][1].x = fmaf(sr4[i].y, m1.z, acc[i][1].x);
                acc[i][1].y = fmaf(sr4[i].y, m1.w, acc[i][1].y);
            }
        } else {
            float4 s2[4];
#pragma unroll
            for (int i = 0; i < 4; ++i)
                s2[i] = *(const float4*)&Ssh[(((rp<<2)+i) << 7) + k];
#pragma unroll
            for (int i = 0; i < 4; ++i) {
                cfma(acc[i][0], s2[i].x, s2[i].y, m0.x, m0.y);
                cfma(acc[i][1], s2[i].x, s2[i].y, m0.z, m0.w);
                cfma(acc[i][0], s2[i].z, s2[i].w, m1.x, m1.y);
                cfma(acc[i][1], s2[i].z, s2[i].w, m1.z, m1.w);
            }
        }
    }
    long base = ((long)p << 14);
#pragma unroll
    for (int i = 0; i < 4; ++i) {
        float4* dst = (float4*)(out + base + ((long)(r0 + (rp<<2) + i) << 7) + (cq<<1));
        *dst = make_float4(acc[i][0].x, acc[i][0].y, acc[i][1].x, acc[i][1].y);
    }
}

// ---------------- lmul body (round-5 proven form) ----------------------------
// A-side rows: wave-uniform global reads. T-side: direct global coalesced row
// reads. Zero LDS, zero barriers. EPI 1: mag/pha  2: abs->cat  3: real->cat
// 4: packed65
template<int EPI>
__device__ inline void lmul_body(const float2* __restrict__ A, const float2* __restrict__ in,
                                 float* __restrict__ o1, float* __restrict__ o2, int coff,
                                 int p, int j0, int t) {
    const float2* T = in + ((long)p << 14);
    int cq = t & 63, rp = t >> 6;
    const float2* Arow[4];
#pragma unroll
    for (int i = 0; i < 4; ++i) {
        int ro = __builtin_amdgcn_readfirstlane((j0 + (rp<<2) + i) << 7);
        Arow[i] = A + ro;
    }
    float2 acc[4][2] = {};
#pragma unroll 8
    for (int k2 = 0; k2 < 64; ++k2) {
        int k = k2 << 1;
        float4 m0 = *(const float4*)&T[(k << 7) + (cq<<1)];
        float4 m1 = *(const float4*)&T[((k+1) << 7) + (cq<<1)];
        float4 s2[4];
#pragma unroll
        for (int i = 0; i < 4; ++i)
            s2[i] = *(const float4*)(Arow[i] + k);
#pragma unroll
        for (int i = 0; i < 4; ++i) {
            if (EPI == 3) {
                acc[i][0].x = fmaf(s2[i].x, m0.x, acc[i][0].x);
                acc[i][0].x = fmaf(-s2[i].y, m0.y, acc[i][0].x);
                acc[i][1].x = fmaf(s2[i].x, m0.z, acc[i][1].x);
                acc[i][1].x = fmaf(-s2[i].y, m0.w, acc[i][1].x);
                acc[i][0].x = fmaf(s2[i].z, m1.x, acc[i][0].x);
                acc[i][0].x = fmaf(-s2[i].w, m1.y, acc[i][0].x);
                acc[i][1].x = fmaf(s2[i].z, m1.z, acc[i][1].x);
                acc[i][1].x = fmaf(-s2[i].w, m1.w, acc[i][1].x);
            } else {
                cfma(acc[i][0], s2[i].x, s2[i].y, m0.x, m0.y);
                cfma(acc[i][1], s2[i].x, s2[i].y, m0.z, m0.w);
                cfma(acc[i][0], s2[i].z, s2[i].w, m1.x, m1.y);
                cfma(acc[i][1], s2[i].z, s2[i].w, m1.z, m1.w);
            }
        }
    }
#pragma unroll
    for (int i = 0; i < 4; ++i) {
        int jj = j0 + (rp<<2) + i;
        int ww0 = cq << 1;
        float2 v0 = acc[i][0], v1 = acc[i][1];
        if (EPI == 1) {
            long idx = ((long)p << 14) + ((long)jj << 7) + ww0;
            *(float2*)&o1[idx] = make_float2(sqrtf(v0.x*v0.x + v0.y*v0.y),
                                             sqrtf(v1.x*v1.x + v1.y*v1.y));
            *(float2*)&o2[idx] = make_float2(atan2f(v0.y, v0.x), atan2f(v1.y, v1.x));
        } else if (EPI == 2) {
            int n = p >> 4, c = p & 15;
            long idx = ((long)(n*48 + coff + c) << 14) + ((long)jj << 7) + ww0;
            *(float2*)&o1[idx] = make_float2(sqrtf(v0.x*v0.x + v0.y*v0.y),
                                             sqrtf(v1.x*v1.x + v1.y*v1.y));
        } else if (EPI == 3) {
            int n = p >> 4, c = p & 15;
            long idx = ((long)(n*48 + coff + c) << 14) + ((long)jj << 7) + ww0;
            *(float2*)&o1[idx] = make_float2(v0.x, v1.x);
        } else if (EPI == 4) {
            if (ww0 < 65) {
                long idx = (long)p*8320 + jj*65 + ww0;
                o1[idx] = sqrtf(v0.x*v0.x + v0.y*v0.y);
                o2[idx] = atan2f(v0.y, v0.x);
                if (ww0 + 1 < 65) {
                    o1[idx+1] = sqrtf(v1.x*v1.x + v1.y*v1.y);
                    o2[idx+1] = atan2f(v1.y, v1.x);
                }
            }
        }
    }
}

// ---------------- dual rmul kernel (+ Mb build at bx>=128) -------------------
// grid (136, 8): bx<128 -> plane (A: 0..63, B: 64..127), by = strip.
// id % 8 == bx % 8 -> all strips of a plane land on one XCD.
template<int LMA, int LMB>
__global__ __launch_bounds__(256, 4)
void k_rmul_dual(const float2* __restrict__ MTa, const float* __restrict__ TrlA,
                 const float* __restrict__ mpA, const float* __restrict__ ppA,
                 float2* __restrict__ outA, int cstartA,
                 const float2* __restrict__ MTb, const float* __restrict__ TrlB,
                 const float* __restrict__ mpB, const float* __restrict__ ppB,
                 float2* __restrict__ outB, int cstartB) {
    __shared__ __align__(16) float2 Ssh[(LMA == 1 && LMB == 1) ? 2 : 16*128];
    __shared__ float2 W[128];
    int bx = blockIdx.x, by = blockIdx.y, t = threadIdx.x;
    if (bx >= 128) {
        int b = (bx - 128)*8 + by;
        if (b < 64) {
            if (t < 128) {
                float ang = TWO_PI_F*(float)t/128.0f;
                float sn, cs; __sincosf(ang, &sn, &cs);
                float invs = 0.08838834764831845f;
                W[t] = make_float2(cs*invs, sn*invs);
            }
            __syncthreads();
            int tid = b*256 + t;
            int o = tid >> 7, m = tid & 127;
            float sr = 0.f, si = 0.f;
            for (int r = 0; r < 128; ++r) {
                float2 a = g_Mf[(o<<7) + r];
                int k = ((r+64)*(m+64)) & 127;
                float2 w = W[k];
                sr += a.x*w.x - a.y*w.y;
                si += a.x*w.y + a.y*w.x;
            }
            float2 v = make_float2(sr, si);
            g_Mb[tid] = v;
            g_MbT[(m<<7) + o] = v;
        }
        return;
    }
    int p = bx & 63, r0 = by << 4;
    if (bx < 64) rmul_body<LMA>(MTa, TrlA, mpA, ppA, outA, cstartA, p, r0, t, Ssh);
    else         rmul_body<LMB>(MTb, TrlB, mpB, ppB, outB, cstartB, p, r0, t, Ssh);
}

// ---------------- dual lmul kernel (XCD-pinned planes, no LDS) ---------------
template<int EPIA, int EPIB>
__global__ __launch_bounds__(256, 4)
void k_lmul_dual(const float2* __restrict__ Aa, const float2* __restrict__ inA,
                 float* __restrict__ o1A, float* __restrict__ o2A, int coffA,
                 const float2* __restrict__ Ab, const float2* __restrict__ inB,
                 float* __restrict__ o1B, float* __restrict__ o2B, int coffB) {
    int bx = blockIdx.x, j0 = blockIdx.y << 4, t = threadIdx.x;
    int p = bx & 63;
    if (bx < 64) lmul_body<EPIA>(Aa, inA, o1A, o2A, coffA, p, j0, t);
    else         lmul_body<EPIB>(Ab, inB, o1B, o2B, coffB, p, j0, t);
}

// ---------------- wave-level 1x1 conv body (float2, KSPLIT=1, no LDS) --------
template<int CIN, int COUT, int OSPLIT>
__device__ inline void wconv_body(const float* __restrict__ in, const float* __restrict__ wgt,
                                  const float* __restrict__ bias, float* __restrict__ out,
                                  int S, int Ctin, int cstart, int Ctout, int costart,
                                  int n, int sblk) {
    constexpr int OW = COUT / OSPLIT;
    int t = threadIdx.x, lane = t & 63;
    int oq = __builtin_amdgcn_readfirstlane(t >> 6);
    int s0 = sblk << 7;
    const float* inb = in + ((long)(n*Ctin + cstart))*S + s0 + (lane<<1);
    const float* wb  = wgt + (oq*OW)*CIN;
    float2 acc[OW];
#pragma unroll
    for (int j = 0; j < OW; ++j) acc[j] = make_float2(0.f, 0.f);
#pragma unroll 4
    for (int c = 0; c < CIN; ++c) {
        float2 xv = *(const float2*)(inb + (long)c*S);
#pragma unroll
        for (int j = 0; j < OW; ++j) {
            float w = wb[j*CIN + c];
            acc[j].x = fmaf(w, xv.x, acc[j].x);
            acc[j].y = fmaf(w, xv.y, acc[j].y);
        }
    }
#pragma unroll
    for (int j = 0; j < OW; ++j) {
        int o = oq*OW + j;
        float b = bias ? bias[o] : 0.f;
        *(float2*)(out + ((long)(n*Ctout + costart + o))*S + s0 + (lane<<1))
            = make_float2(acc[j].x + b, acc[j].y + b);
    }
}

// ---------------- float4 wave-conv body (4 px/thread, 1KB/load-instr) --------
template<int CIN, int COUT, int OSPLIT>
__device__ inline void wconv4_body(const float* __restrict__ in, const float* __restrict__ wgt,
                                   float* __restrict__ out,
                                   int S, int Ctin, int cstart, int Ctout, int costart,
                                   int n, int sblk) {
    constexpr int OW = COUT / OSPLIT;
    int t = threadIdx.x, lane = t & 63;
    int oq = __builtin_amdgcn_readfirstlane(t >> 6);
    int s0 = sblk << 8;                      // 256 px per block
    const float* inb = in + ((long)(n*Ctin + cstart))*S + s0 + (lane<<2);
    const float* wb  = wgt + (oq*OW)*CIN;
    float4 acc[OW];
#pragma unroll
    for (int j = 0; j < OW; ++j) acc[j] = make_float4(0.f, 0.f, 0.f, 0.f);
#pragma unroll 8
    for (int c = 0; c < CIN; ++c) {
        float4 xv = *(const float4*)(inb + (long)c*S);
#pragma unroll
        for (int j = 0; j < OW; ++j) {
            float w = wb[j*CIN + c];
            acc[j].x = fmaf(w, xv.x, acc[j].x);
            acc[j].y = fmaf(w, xv.y, acc[j].y);
            acc[j].z = fmaf(w, xv.z, acc[j].z);
            acc[j].w = fmaf(w, xv.w, acc[j].w);
        }
    }
#pragma unroll
    for (int j = 0; j < OW; ++j) {
        int o = oq*OW + j;
        *(float4*)(out + ((long)(n*Ctout + costart + o))*S + s0 + (lane<<2)) = acc[j];
    }
}

// ---------------- stage 1: conv1 + matrix builder ----------------------------
// grid (64,4,3): z<2 -> compute 24-output half via float4 body (4 waves x 6
// outputs, 256 px/block, 1KB/load-instr, unroll 8 -> 8KB in flight/wave);
// z==2 -> builder (b = by*64+bx < 64).
__global__ __launch_bounds__(256, 4)
void k_conv1_build(const float* __restrict__ x, const float* __restrict__ w,
                   float* __restrict__ x1) {
    int z = blockIdx.z;
    if (z < 2) {
        wconv4_body<192,24,4>(x, w + z*24*192, x1, 16384, 192, 0, 48, z*24,
                              blockIdx.y, blockIdx.x);
    } else {
        int b = blockIdx.y*gridDim.x + blockIdx.x;
        if (b < 64) build_A_body(b*256 + threadIdx.x);
    }
}

// ---------------- stage 7: conv2 ---------------------------------------------
// grid (128,4,2): z selects 96-output half; 4 waves x 24 outputs each,
// KSPLIT=1, zero LDS, LB(256,4) -> 1024 blocks = 4 blocks/CU.
__global__ __launch_bounds__(256, 4)
void k_conv2(const float* __restrict__ in, const float* __restrict__ wgt,
             float* __restrict__ out) {
    int z = blockIdx.z;
    wconv_body<48,96,4>(in, wgt + z*96*48, nullptr, out, 16384, 48, 0, 192, z*96,
                        blockIdx.y, blockIdx.x);
}

// ---------------- pointwise stage: maskconv + 4 channel-mixes ----------------
__device__ inline void mix16b(const float* __restrict__ in, const float* __restrict__ w,
                              const float* __restrict__ b, float* __restrict__ out,
                              int Ctin, int S, int n, int s0base, int Slim) {
    int t = threadIdx.x, lane = t & 63;
    int wv = __builtin_amdgcn_readfirstlane(t >> 6);
    int oq = wv & 3, pg = wv >> 2;
    int s0 = s0base + (pg << 7);
    if (s0 >= Slim) return;                    // no __syncthreads in this path
    const float* inb = in + ((long)(n*Ctin))*S + s0 + (lane<<1);
    float2 acc[4];
#pragma unroll
    for (int j = 0; j < 4; ++j) {
        float bb = b ? b[oq*4 + j] : 0.f;
        acc[j] = make_float2(bb, bb);
    }
#pragma unroll
    for (int half = 0; half < 2; ++half) {
        float2 xv[8];
#pragma unroll
        for (int c = 0; c < 8; ++c)
            xv[c] = *(const float2*)(inb + (long)(half*8 + c)*S);
#pragma unroll
        for (int c = 0; c < 8; ++c) {
#pragma unroll
            for (int j = 0; j < 4; ++j) {
                float ww = w[(oq*4 + j)*16 + half*8 + c];
                acc[j].x = fmaf(ww, xv[c].x, acc[j].x);
                acc[j].y = fmaf(ww, xv[c].y, acc[j].y);
            }
        }
    }
#pragma unroll
    for (int j = 0; j < 4; ++j) {
        int o = oq*4 + j;
        *(float2*)(out + ((long)(n*Ctin + o))*S + s0 + (lane<<1)) = acc[j];
    }
}

__device__ inline void maskconv_body(const float* __restrict__ mag, const float* __restrict__ ws3,
                                     const float* __restrict__ bs, const float* __restrict__ wf,
                                     const float* __restrict__ bf, const float* __restrict__ wm,
                                     const float* __restrict__ bm, float* __restrict__ out,
                                     int n, int tile, float* patch) {
    int h0 = (tile >> 3) << 4, w0 = (tile & 7) << 4;
    int t = threadIdx.x;
    const float* magn = mag + ((long)n << 18);
    for (int idx = t; idx < 16*324; idx += 1024) {
        int c = idx / 324, r = idx - c*324;
        int ph = r / 18, pw = r - ph*18;
        int gh = h0 - 1 + ph, gw = w0 - 1 + pw;
        float v = 0.f;
        if (gh >= 19 && gh < 109 && gw >= 19 && gw < 109)
            v = magn[(c<<14) + (gh<<7) + gw];
        patch[c*324 + r] = v;
    }
    __syncthreads();
    int oq = t >> 8, pix = t & 255;
    int ty = pix >> 4, tx = pix & 15;
    int h = h0 + ty, w = w0 + tx;
    bool in1 = (h >= 19 && h < 109 && w >= 19 && w < 109);
    unsigned long long bal = __ballot(in1);
    float res[4];
    if (bal != 0ull) {
        float acc[4];
#pragma unroll
        for (int j = 0; j < 4; ++j) acc[j] = bs[oq*4 + j];
        for (int c = 0; c < 16; ++c) {
            const float* pc = patch + c*324 + ty*18 + tx;
            const float* wc = ws3 + c*9;
#pragma unroll
            for (int dh = 0; dh < 3; ++dh) {
#pragma unroll
                for (int dw = 0; dw < 3; ++dw) {
                    float tap = pc[dh*18 + dw];
#pragma unroll
                    for (int j = 0; j < 4; ++j)
                        acc[j] = fmaf(wc[(oq*4 + j)*144 + dh*3 + dw], tap, acc[j]);
                }
            }
        }
#pragma unroll
        for (int j = 0; j < 4; ++j) res[j] = acc[j];
    }
    if (bal != ~0ull) {
        float acc2[4];
#pragma unroll
        for (int j = 0; j < 4; ++j) acc2[j] = bf[oq*4 + j];
#pragma unroll
        for (int half = 0; half < 2; ++half) {
            float xv[8];
#pragma unroll
            for (int c = 0; c < 8; ++c)
                xv[c] = magn[((half*8 + c)<<14) + (h<<7) + w];
#pragma unroll
            for (int c = 0; c < 8; ++c)
#pragma unroll
                for (int j = 0; j < 4; ++j)
                    acc2[j] = fmaf(wf[(oq*4 + j)*16 + half*8 + c], xv[c], acc2[j]);
        }
        if (!in1) {
#pragma unroll
            for (int j = 0; j < 4; ++j) res[j] = acc2[j];
        }
    }
    __syncthreads();               // all reads of patch complete
    float* resl = patch;           // reuse as [16][256]
#pragma unroll
    for (int j = 0; j < 4; ++j) resl[(oq*4 + j)*256 + pix] = res[j];
    __syncthreads();
    float rr[16];
#pragma unroll
    for (int o = 0; o < 16; ++o) rr[o] = resl[o*256 + pix];
#pragma unroll
    for (int j = 0; j < 4; ++j) {
        int o2 = oq*4 + j;
        float a = bm[o2];
#pragma unroll
        for (int o = 0; o < 16; ++o)
            a = fmaf(wm[o2*16 + o], rr[o], a);
        out[((long)((n<<4) + o2) << 14) + (h << 7) + w] = a;
    }
}

__global__ __launch_bounds__(1024, 8)
void k_point(const float* __restrict__ mag, const float* __restrict__ ws3,
             const float* __restrict__ bs, const float* __restrict__ wf,
             const float* __restrict__ bf, const float* __restrict__ wm,
             const float* __restrict__ bm, float* __restrict__ t2,
             const float* __restrict__ pha, const float* __restrict__ pw,
             const float* __restrict__ pb, float* __restrict__ t1,
             const float* __restrict__ x1, const float* __restrict__ c0w,
             const float* __restrict__ c0b, float* __restrict__ cat,
             const float* __restrict__ m65, const float* __restrict__ p65,
             const float* __restrict__ c1w, const float* __restrict__ c1b,
             float* __restrict__ t3, float* __restrict__ t4) {
    __shared__ float patch[16*324];
    int b = blockIdx.x;
    if (b < 256) {
        maskconv_body(mag, ws3, bs, wf, bf, wm, bm, t2, b >> 6, b & 63, patch);
    } else if (b < 384) {
        int i = b - 256;               // pha channel-mix (S=16384): 32 blocks/n
        mix16b(pha, pw, pb, t1, 16, 16384, i >> 5, (i & 31) << 9, 16384);
    } else if (b < 512) {
        int i = b - 384;               // conv_0: x1 ch0..15 -> cat ch0..15 (Ct=48)
        mix16b(x1, c0w, c0b, cat, 48, 16384, i >> 5, (i & 31) << 9, 16384);
    } else if (b < 580) {
        int i = b - 512;               // m65 mix (S=8320): 17 blocks/n
        mix16b(m65, c1w, c1b, t3, 16, 8320, i / 17, (i % 17) << 9, 8320);
    } else {
        int i = b - 580;               // p65 mix
        mix16b(p65, c1w, c1b, t4, 16, 8320, i / 17, (i % 17) << 9, 8320);
    }
}

// ---------------- launch ----------------------------------------------------
extern "C" void kernel_launch(void* const* d_in, const int* in_sizes, int n_in,
                              void* d_out, int out_size, void* d_ws, size_t ws_size,
                              hipStream_t stream) {
    (void)in_sizes; (void)n_in; (void)out_size; (void)d_ws; (void)ws_size;
    const float* x        = (const float*)d_in[0];
    const float* conv1_w  = (const float*)d_in[1];
    const float* mag_s_w  = (const float*)d_in[2];
    const float* mag_s_b  = (const float*)d_in[3];
    const float* mag_f_w  = (const float*)d_in[4];
    const float* mag_f_b  = (const float*)d_in[5];
    const float* mag_w_   = (const float*)d_in[6];
    const float* mag_b_   = (const float*)d_in[7];
    const float* pha_w_   = (const float*)d_in[8];
    const float* pha_b_   = (const float*)d_in[9];
    const float* conv_0_w = (const float*)d_in[10];
    const float* conv_0_b = (const float*)d_in[11];
    const float* conv_1_w = (const float*)d_in[12];
    const float* conv_1_b = (const float*)d_in[13];
    const float* conv2_w  = (const float*)d_in[14];
    float* outp = (float*)d_out;

    float2 *Mf, *MfT, *Mb, *MbT, *Fm, *IFm, *bufA, *bufB;
    float *x1, *mag, *pha, *m65, *p65, *t1, *t2, *t3, *t4, *cat;
    hipGetSymbolAddress((void**)&Mf,   HIP_SYMBOL(g_Mf));
    hipGetSymbolAddress((void**)&MfT,  HIP_SYMBOL(g_MfT));
    hipGetSymbolAddress((void**)&Mb,   HIP_SYMBOL(g_Mb));
    hipGetSymbolAddress((void**)&MbT,  HIP_SYMBOL(g_MbT));
    hipGetSymbolAddress((void**)&Fm,   HIP_SYMBOL(g_F));
    hipGetSymbolAddress((void**)&IFm,  HIP_SYMBOL(g_IF));
    hipGetSymbolAddress((void**)&bufA, HIP_SYMBOL(g_bufA));
    hipGetSymbolAddress((void**)&bufB, HIP_SYMBOL(g_bufB));
    hipGetSymbolAddress((void**)&x1,   HIP_SYMBOL(g_x1));
    hipGetSymbolAddress((void**)&mag,  HIP_SYMBOL(g_mag));
    hipGetSymbolAddress((void**)&pha,  HIP_SYMBOL(g_pha));
    hipGetSymbolAddress((void**)&m65,  HIP_SYMBOL(g_m65));
    hipGetSymbolAddress((void**)&p65,  HIP_SYMBOL(g_p65));
    hipGetSymbolAddress((void**)&t1,   HIP_SYMBOL(g_t1));
    hipGetSymbolAddress((void**)&t2,   HIP_SYMBOL(g_t2));
    hipGetSymbolAddress((void**)&t3,   HIP_SYMBOL(g_t3));
    hipGetSymbolAddress((void**)&t4,   HIP_SYMBOL(g_t4));
    hipGetSymbolAddress((void**)&cat,  HIP_SYMBOL(g_cat));

    dim3 bt(256, 1, 1);

    // stage 1: conv1 (x -> x1, z<2, float4 body) + build Mf/MfT/F/IF (z==2)
    k_conv1_build<<<dim3(64,4,3), bt, 0, stream>>>(x, conv1_w, x1);

    // stage 2: dual rmul (FRFT fwd -> bufA; FFT fwd -> bufB) + build Mb
    k_rmul_dual<1,1><<<dim3(136,8), bt, 0, stream>>>(
        MfT, x1, nullptr, nullptr, bufA, 16,
        Fm,  x1, nullptr, nullptr, bufB, 32);

    // stage 3: dual lmul (mag/pha full <- bufA; packed65 <- bufB)
    k_lmul_dual<1,4><<<dim3(128,8), bt, 0, stream>>>(
        Mf, bufA, mag, pha, 0,
        Fm, bufB, m65, p65, 0);

    // stage 4: maskconv(+mag mix) | pha mix | conv_0 | m65 mix | p65 mix
    k_point<<<648, dim3(1024,1,1), 0, stream>>>(mag, mag_s_w, mag_s_b, mag_f_w, mag_f_b,
                                                mag_w_, mag_b_, t2,
                                                pha, pha_w_, pha_b_, t1,
                                                x1, conv_0_w, conv_0_b, cat,
                                                m65, p65, conv_1_w, conv_1_b, t3, t4);

    // stage 5: dual rmul (FRFT bwd combine(t2,t1) -> bufA; irfft combine65(t3,t4) -> bufB)
    k_rmul_dual<2,3><<<dim3(128,8), bt, 0, stream>>>(
        MbT, nullptr, t2, t1, bufA, 0,
        IFm, nullptr, t3, t4, bufB, 0);

    // stage 6: dual lmul (abs -> cat ch16..31; real -> cat ch32..47)
    k_lmul_dual<2,3><<<dim3(128,8), bt, 0, stream>>>(
        Mb,  bufA, cat, nullptr, 16,
        IFm, bufB, cat, nullptr, 32);

    // stage 7: conv2 (cat -> out)
    k_conv2<<<dim3(128,4,2), bt, 0, stream>>>(cat, conv2_w, outp);
}